// Round 15
// baseline (255.414 us; speedup 1.0000x reference)
//
#include <hip/hip_runtime.h>
#include <hip/hip_cooperative_groups.h>
#include <math.h>

namespace cg = cooperative_groups;

static constexpr int IMGS = 2;
static constexpr int H = 128, W = 128;
static constexpr int NP = H * W;           // 16384
static constexpr int KWIN = 30;            // quickshift window radius (ceil(3*10))
static constexpr int PR = 20;              // parent prune radius: dr^2+dc^2>400 can't win (MAX_DIST=20)
static constexpr int GR = 20;              // gaussian radius int(4*5+0.5)
static constexpr float INV = 0.005f;       // 0.5 / (10*10)
static constexpr int MAXSEG = 40;

// padded feature layout: row stride 192 float4, cols [30,158) hold the image.
// float4 = (L, a, b, dens); pads = (1e6,1e6,1e6,-inf).
static constexpr int PSTR = 192;
static constexpr int PIMG = H * PSTR;      // 24576 float4 per image
static constexpr int NSEG = 64 + 2 * PR;   // 104 staged float4 per k_par row

typedef float f32x2 __attribute__((ext_vector_type(2)));

// ---------------- fused prep + blur (cooperative, R30: launch-count cut) -------
// Phase 1 = old k_prep (sentinel fill + rgb2lab), phase 2 = old k_blur —
// bodies byte-identical to R14's kernels; grid.sync() replaces the launch gap.
__global__ __launch_bounds__(384)
void k_prepblur(const float* __restrict__ x, float4* __restrict__ pf,
                float4* __restrict__ bufL) {
#pragma clang fp contract(off)
  {                                        // ---- phase 1: prep (no early return)
    int i = blockIdx.x * 384 + threadIdx.x;   // 0..98303 covers 49152
    if (i < IMGS * PIMG) pf[i] = make_float4(1e6f, 1e6f, 1e6f, -__builtin_inff());
    if (i < IMGS * NP) {
      int img = i / NP, p = i % NP;
      const float* base = x + img * 3 * NP;
      float rgb[3] = { base[p], base[NP + p], base[2 * NP + p] };
      float lin[3];
      for (int c = 0; c < 3; ++c) {
        float v = rgb[c];
        lin[c] = (v > 0.04045f) ? powf((v + 0.055f) / 1.055f, 2.4f) : (v / 12.92f);
      }
      const float M[3][3] = {{0.412453f, 0.357580f, 0.180423f},
                             {0.212671f, 0.715160f, 0.072169f},
                             {0.019334f, 0.119193f, 0.950227f}};
      const float wp[3] = {0.95047f, 1.0f, 1.08883f};
      float f[3];
      for (int j = 0; j < 3; ++j) {
        float s = lin[0] * M[j][0];
        s = s + lin[1] * M[j][1];
        s = s + lin[2] * M[j][2];
        float xyz = s / wp[j];
        f[j] = (xyz > 0.008856f) ? cbrtf(fmaxf(xyz, 1e-8f))
                                 : (7.787f * xyz + (float)(16.0 / 116.0));
      }
      float L = 116.0f * f[1] - 16.0f;
      float a = 500.0f * (f[0] - f[1]);
      float b = 200.0f * (f[1] - f[2]);
      bufL[i] = make_float4(L, a, b, 0.0f);
    }
  }
  cg::this_grid().sync();                  // all lab values visible
  {                                        // ---- phase 2: blur (old k_blur body)
    __shared__ float w[2 * GR + 1];
    __shared__ float mid[3][128];
    if (threadIdx.x == 0) {
      double k[2 * GR + 1];
      double s = 0.0;
      for (int i = -GR; i <= GR; ++i) {
        double t = (double)i / 5.0;
        double v = exp(-0.5 * t * t);
        k[i + GR] = v;
        s += v;
      }
      for (int i = 0; i < 2 * GR + 1; ++i) w[i] = (float)(k[i] / s);
    }
    __syncthreads();
    int tid = threadIdx.x;
    int c = tid >> 7;                       // 0..2
    int xx = tid & 127;
    int b = blockIdx.x;                     // img*128 + y
    int y = b & 127, img = b >> 7;
    const float* base = (const float*)(bufL + img * NP);
    float a = 0.0f;
    for (int t = 0; t <= 2 * GR; ++t) {
      int yy = y - GR + t;
      if (yy < 0) yy = -yy - 1;
      if (yy >= H) yy = 2 * H - 1 - yy;
      a = a + w[t] * base[(yy * W + xx) * 4 + c];
    }
    mid[c][xx] = a;
    __syncthreads();
    float o = 0.0f;
    for (int t = 0; t <= 2 * GR; ++t) {
      int xq = xx - GR + t;
      if (xq < 0) xq = -xq - 1;
      if (xq >= W) xq = 2 * W - 1 - xq;
      o = o + w[t] * mid[c][xq];
    }
    ((float*)(pf + img * PIMG + y * PSTR + xx + KWIN))[c] = o;  // 4B store
  }
}

// ---------------- density: 2-center rows x 4-way row-split, barrier-free -------
// (validated best: 50.4us @ R11/R14. 4-center (R12) spills — do not revisit.
// Density keeps the FULL 61x61 window: no distance cutoff, far terms ~exp(-2).)
__device__ inline void dens_row2(const float4* __restrict__ grow,
                                 float4 fc0, float4 fc1,
                                 float sprf0, float sprf1, int lane,
                                 float& acc0, float& acc1) {
#pragma clang fp contract(off)
  const f32x2 nInv = { -INV, -INV };
#pragma unroll
  for (int d0 = 0; d0 + 1 < 61; d0 += 2) {
    float4 nb0 = grow[lane + d0];
    float4 nb1 = grow[lane + d0 + 1];
    float c0 = (float)((d0 - KWIN) * (d0 - KWIN));
    float c1 = (float)((d0 + 1 - KWIN) * (d0 + 1 - KWIN));
    // center 0
    f32x2 dx0 = { fc0.x - nb0.x, fc0.x - nb1.x };
    f32x2 dy0 = { fc0.y - nb0.y, fc0.y - nb1.y };
    f32x2 dz0 = { fc0.z - nb0.z, fc0.z - nb1.z };
    f32x2 dd0 = (dx0 * dx0 + dy0 * dy0) + dz0 * dz0;
    f32x2 sp0 = { sprf0 + c0, sprf0 + c1 };   // exact: ints < 2^11 (or inf)
    dd0 = dd0 + sp0;
    f32x2 e0 = dd0 * nInv;                    // bit == -(d*INV)
    acc0 = acc0 + __expf(e0.x);               // in-order within row
    acc0 = acc0 + __expf(e0.y);
    // center 1 (same loaded neighbors)
    f32x2 dx1 = { fc1.x - nb0.x, fc1.x - nb1.x };
    f32x2 dy1 = { fc1.y - nb0.y, fc1.y - nb1.y };
    f32x2 dz1 = { fc1.z - nb0.z, fc1.z - nb1.z };
    f32x2 dd1 = (dx1 * dx1 + dy1 * dy1) + dz1 * dz1;
    f32x2 sp1 = { sprf1 + c0, sprf1 + c1 };
    dd1 = dd1 + sp1;
    f32x2 e1 = dd1 * nInv;
    acc1 = acc1 + __expf(e1.x);
    acc1 = acc1 + __expf(e1.y);
  }
  {                                           // dc = 60 tail, both centers
    float4 nb = grow[lane + 60];
    float ct = (float)((60 - KWIN) * (60 - KWIN));
    float a0 = fc0.x - nb.x, a1 = fc0.y - nb.y, a2 = fc0.z - nb.z;
    float d0 = (a0 * a0 + a1 * a1) + a2 * a2;
    d0 = d0 + (sprf0 + ct);
    acc0 = acc0 + __expf(-d0 * INV);
    float b0 = fc1.x - nb.x, b1 = fc1.y - nb.y, b2 = fc1.z - nb.z;
    float d1 = (b0 * b0 + b1 * b1) + b2 * b2;
    d1 = d1 + (sprf1 + ct);
    acc1 = acc1 + __expf(-d1 * INV);
  }
}

__global__ __launch_bounds__(512, 4)
void k_dens(const float4* __restrict__ pf, float* __restrict__ part) {
#pragma clang fp contract(off)
  __shared__ float pbuf[8][2][64];
  int tid = threadIdx.x;
  int lane = tid & 63;
  int wave = tid >> 6;
  int b = blockIdx.x;                      // 1024: img*512 + ygrp*8 + tile*4 + q
  int q = b & 3, tile = (b >> 2) & 1, ygrp = (b >> 3) & 63, img = b >> 9;
  int y0 = ygrp * 2, y1 = y0 + 1;
  int x0 = tile * 64;
  const float4* fimg = pf + img * PIMG;
  float4 fc0 = fimg[y0 * PSTR + x0 + lane + KWIN];
  float4 fc1 = fimg[y1 * PSTR + x0 + lane + KWIN];
  int lo = y0 - KWIN; if (lo < 0) lo = 0;
  int hi = y1 + KWIN; if (hi > H - 1) hi = H - 1;
  int nr = hi - lo + 1;                    // 32..62 union rows
  int c = q * 8 + wave;                    // 0..31 ascending row chunks
  int base = nr >> 5, rem = nr & 31;       // base>=1, so all chunks nonempty
  int cnt = base + (c < rem ? 1 : 0);
  int start = lo + c * base + (c < rem ? c : rem);
  float acc0 = 0.0f, acc1 = 0.0f;
  for (int r = 0; r < cnt; ++r) {
    int ny = start + r;
    int dr0 = ny - y0, dr1 = ny - y1;
    // wave-uniform activity guards; inactive => sprf=inf => exact +0.0 terms
    float s0 = (ny <= y0 + KWIN) ? (float)(dr0 * dr0) : __builtin_inff();
    float s1 = (ny >= y1 - KWIN) ? (float)(dr1 * dr1) : __builtin_inff();
    const float4* grow = fimg + ny * PSTR + x0;
    dens_row2(grow, fc0, fc1, s0, s1, lane, acc0, acc1);
  }
  pbuf[wave][0][lane] = acc0;              // publish row-chunk partials
  pbuf[wave][1][lane] = acc1;
  __syncthreads();
  if (wave < 2) {                          // wave w folds center row y0+w
    float a = pbuf[0][wave][lane];
#pragma unroll
    for (int w = 1; w < 8; ++w) a = a + pbuf[w][wave][lane];
    part[q * (IMGS * NP) + img * NP + (y0 + wave) * W + x0 + lane] = a;
  }
}

// ---------------- fold the 4 row-quarter partials into pf.w --------------------
// Ascending-q = ascending-row order, left-to-right: bitwise-deterministic.
__global__ void k_densmerge(const float* __restrict__ part, float4* __restrict__ pf) {
#pragma clang fp contract(off)
  int i = blockIdx.x * blockDim.x + threadIdx.x;
  if (i >= IMGS * NP) return;
  int img = i / NP, p = i % NP, y = p >> 7, x = p & 127;
  float s = ((part[i] + part[IMGS * NP + i]) + part[2 * IMGS * NP + i])
            + part[3 * IMGS * NP + i];
  pf[img * PIMG + y * PSTR + x + KWIN].w = s;
}

// ---------------- parent: +-20 pruned window, half-split, AoS b128, pairs ------
// (R11, validated: semantic prune — MAX_DIST=20 means dr^2+dc^2>400 candidates
// can never be sub-threshold winners; 41x41 window = 45% of the work.)
template<int DB, int DE>
__device__ inline void par_pairs(const float4* __restrict__ rb,
                                 int lane, f32x2 fcx, f32x2 fcy, f32x2 fcz,
                                 float dcen, float sprf, int qbase,
                                 float& bestd, int& bestp) {
#pragma clang fp contract(off)
#pragma unroll
  for (int d0 = DB; d0 + 1 < DE; d0 += 2) {
    int i0 = lane + d0;
    float4 nb0 = rb[i0];
    float4 nb1 = rb[i0 + 1];
    f32x2 nx = { nb0.x, nb1.x };
    f32x2 nv = { nb0.y, nb1.y };
    f32x2 nz = { nb0.z, nb1.z };
    f32x2 nw = { nb0.w, nb1.w };
    f32x2 dx = fcx - nx, dy = fcy - nv, dz = fcz - nz;
    f32x2 dd = (dx * dx + dy * dy) + dz * dz;
    f32x2 sp = { sprf + (float)((d0 - PR) * (d0 - PR)),
                 sprf + (float)((d0 + 1 - PR) * (d0 + 1 - PR)) };
    dd = dd + sp;                          // exact (ints < 2^11)
    int b0 = (nw.x > dcen) & (dd.x < bestd);
    bestd = b0 ? dd.x : bestd;
    bestp = b0 ? (qbase + d0 - PR) : bestp;
    int b1 = (nw.y > dcen) & (dd.y < bestd);
    bestd = b1 ? dd.y : bestd;
    bestp = b1 ? (qbase + d0 + 1 - PR) : bestp;
  }
  if constexpr ((DE - DB) & 1) {           // scalar tail
    constexpr int dcu = DE - 1;
    float4 nb = rb[lane + dcu];
    float nd = nb.w;
    float d0 = fcx.x - nb.x, d1 = fcy.x - nb.y, d2 = fcz.x - nb.z;
    float d = (d0 * d0 + d1 * d1) + d2 * d2;
    d = d + (sprf + (float)((dcu - PR) * (dcu - PR)));
    int bt = (nd > dcen) & (d < bestd);
    bestd = bt ? d : bestd;
    bestp = bt ? (qbase + dcu - PR) : bestp;
  }
}

template<int DB, int DE>
__device__ inline void par_two_rows(const float4* __restrict__ bufA,
                                    const float4* __restrict__ bufB,
                                    int lane, f32x2 fcx, f32x2 fcy, f32x2 fcz,
                                    float dcen, int y, int x,
                                    int nyA, bool haveB,
                                    float& bestd, int& bestp) {
#pragma clang fp contract(off)
  int drA = nyA - y;
  par_pairs<DB, DE>(bufA, lane, fcx, fcy, fcz, dcen,
                    (float)(drA * drA), nyA * W + x, bestd, bestp);
  if (haveB) {
    int drB = nyA + 1 - y;
    par_pairs<DB, DE>(bufB, lane, fcx, fcy, fcz, dcen,
                      (float)(drB * drB), (nyA + 1) * W + x, bestd, bestp);
  }
}

__global__ __launch_bounds__(512, 4)
void k_par(const float4* __restrict__ pf, unsigned long long* __restrict__ pkeys) {
#pragma clang fp contract(off)
  __shared__ float4 aos[2][2][NSEG];       // [buf][row-of-pair][col]
  __shared__ unsigned long long m_k[8][64];
  int tid = threadIdx.x, lane = tid & 63, wave = tid >> 6;
  int b = blockIdx.x;                      // img*512 + y*4 + tile*2 + half
  int half = b & 1, tile = (b >> 1) & 1, y = (b >> 2) & 127, img = b >> 9;
  int x0 = tile * 64, x = x0 + lane;
  const float4* fimg = pf + img * PIMG;
  float4 fc = fimg[y * PSTR + x + KWIN];
  float dcen = fc.w;
  f32x2 fcx = { fc.x, fc.x }, fcy = { fc.y, fc.y }, fcz = { fc.z, fc.z };
  int ny0 = y - PR; if (ny0 < 0) ny0 = 0;
  int ny1 = y + PR; if (ny1 > H - 1) ny1 = H - 1;
  int nr = ny1 - ny0 + 1;                  // 21..41
  int h0 = nr >> 1;                        // rows in half 0
  int hb = half ? (ny0 + h0) : ny0;
  int he = half ? (ny1 + 1) : (ny0 + h0);
  int cnt = he - hb;                       // >= 10
  // pair staging: 2 rows x NSEG float4 = 2*208 float2; threads 0..207 stage
  // row A (float2 index sidx), threads 256..463 stage row B.
  int rsel = tid >> 8;                     // 0..1
  int sidx = tid & 255;                    // float2 index within row
  const int segoff = x0 + (KWIN - PR);     // staged cols = x0-PR .. x0+63+PR
  {
    int rA = hb;
    int rB = (hb + 1 < he) ? hb + 1 : hb;  // clamp (unused if no row B)
    int rr = rsel ? rB : rA;
    if (sidx < NSEG * 2) {
      float2 v = *(const float2*)(((const float*)(fimg + rr * PSTR + segoff)) + sidx * 2);
      *(float2*)(((float*)&aos[0][rsel][0]) + sidx * 2) = v;
    }
  }
  __syncthreads();
  float bestd = __builtin_inff();
  int bestp = y * W + x;
  int npairs = (cnt + 1) >> 1;
  for (int p = 0; p < npairs; ++p) {
    int kb = p & 1;
    float2 pv;
    bool pre = (p + 1 < npairs);
    if (pre) {                             // issue next-pair global loads early
      int nA = hb + 2 * (p + 1);
      int nB = (nA + 1 < he) ? nA + 1 : nA;
      int pr_row = rsel ? nB : nA;
      if (sidx < NSEG * 2)
        pv = *(const float2*)(((const float*)(fimg + pr_row * PSTR + segoff)) + sidx * 2);
    }
    int nyA = hb + 2 * p;
    bool haveB = (nyA + 1 < he);           // wave-uniform
    const float4* bufA = &aos[kb][0][0];
    const float4* bufB = &aos[kb][1][0];
    if      (wave == 0) par_two_rows< 0,  6>(bufA, bufB, lane, fcx, fcy, fcz, dcen, y, x, nyA, haveB, bestd, bestp);
    else if (wave == 1) par_two_rows< 6, 11>(bufA, bufB, lane, fcx, fcy, fcz, dcen, y, x, nyA, haveB, bestd, bestp);
    else if (wave == 2) par_two_rows<11, 16>(bufA, bufB, lane, fcx, fcy, fcz, dcen, y, x, nyA, haveB, bestd, bestp);
    else if (wave == 3) par_two_rows<16, 21>(bufA, bufB, lane, fcx, fcy, fcz, dcen, y, x, nyA, haveB, bestd, bestp);
    else if (wave == 4) par_two_rows<21, 26>(bufA, bufB, lane, fcx, fcy, fcz, dcen, y, x, nyA, haveB, bestd, bestp);
    else if (wave == 5) par_two_rows<26, 31>(bufA, bufB, lane, fcx, fcy, fcz, dcen, y, x, nyA, haveB, bestd, bestp);
    else if (wave == 6) par_two_rows<31, 36>(bufA, bufB, lane, fcx, fcy, fcz, dcen, y, x, nyA, haveB, bestd, bestp);
    else                par_two_rows<36, 41>(bufA, bufB, lane, fcx, fcy, fcz, dcen, y, x, nyA, haveB, bestd, bestp);
    if (pre && sidx < NSEG * 2)            // write other buffer: no race now
      *(float2*)(((float*)&aos[kb ^ 1][rsel][0]) + sidx * 2) = pv;
    __syncthreads();                       // publish next pair
  }
  // pack (d, q): inf (no candidate) sorts above all finite d
  m_k[wave][lane] =
      ((unsigned long long)__float_as_uint(bestd) << 32) | (unsigned)bestp;
  __syncthreads();
  if (wave == 0) {
    unsigned long long k = m_k[0][lane];
#pragma unroll
    for (int w = 1; w < 8; ++w) {
      unsigned long long kw = m_k[w][lane];
      k = (kw < k) ? kw : k;
    }
    pkeys[half * (IMGS * NP) + img * NP + y * W + x] = k;
  }
}

// ---------------- fused merge + root + scan + label (cooperative) --------------
// R30: merges k_merge, k_root, k_scanlabel into one cooperative kernel.
// Phase M (all blocks): decode pkeys -> parent, root=-1 (old k_merge, identical).
// grid.sync. Phase R (all blocks): root chase (old k_root, identical racy-safe
// shortcut) — runs concurrently with Phase S (blocks 0..IMGS-1): root-flag scan
// into cums (512 thr x 32 elems, same flags/prefix math as old k_scanlabel;
// R and S touch disjoint arrays). grid.sync. Phase L (all blocks): labels.
__global__ __launch_bounds__(512)
void k_mrs(const unsigned long long* __restrict__ pkeys, int* __restrict__ parent,
           int* __restrict__ root, int* __restrict__ cums, int* __restrict__ out) {
  __shared__ int partl[512];
  int t = threadIdx.x;
  int gid = blockIdx.x * 512 + t;          // 0..131071 covers 32768
  // ---- phase M: merge halves -> parent, init root=-1
  if (gid < IMGS * NP) {
    unsigned long long k0 = pkeys[gid], k1 = pkeys[IMGS * NP + gid];
    unsigned long long k = (k0 < k1) ? k0 : k1;
    float bd = __uint_as_float((unsigned)(k >> 32));
    int p = gid % NP;
    parent[gid] = (bd > 400.0f) ? p : (int)(k & 0xffffffffu);  // sqrt(d)>max_dist
    root[gid] = -1;                        // enables the chase shortcut
  }
  cg::this_grid().sync();
  // ---- phase R: root chase (all blocks) — writes root[] only
  if (gid < IMGS * NP) {
    int img = gid / NP, p = gid % NP;
    const int* par = parent + img * NP;
    volatile int* rt = (volatile int*)(root + img * NP);
    int r = par[p];
#pragma unroll 1
    for (int it = 0; it < NP; ++it) {      // chains strictly increase density
      int rr = rt[r];                      // published root of r (or -1)
      int pr = par[r];
      if (rr >= 0) { r = rr; break; }
      if (pr == r) break;
      r = pr;
    }
    root[gid] = r;
  }
  // ---- phase S: per-image scan (blocks 0..IMGS-1) — writes cums[] only
  if (blockIdx.x < IMGS) {
    int img = blockIdx.x;
    const int* par = parent + img * NP;
    int base = t * 32;                     // 512 threads x 32 elements
    int f[32];
    const int4* p4 = (const int4*)(par + base);
#pragma unroll
    for (int j = 0; j < 8; ++j) {
      int4 v = p4[j];
      f[4 * j + 0] = (v.x == base + 4 * j + 0);
      f[4 * j + 1] = (v.y == base + 4 * j + 1);
      f[4 * j + 2] = (v.z == base + 4 * j + 2);
      f[4 * j + 3] = (v.w == base + 4 * j + 3);
    }
    int s = 0;
#pragma unroll
    for (int j = 0; j < 32; ++j) s += f[j];
    partl[t] = s;
    __syncthreads();
    for (int off = 1; off < 512; off <<= 1) {
      int add = (t >= off) ? partl[t - off] : 0;
      __syncthreads();
      partl[t] += add;
      __syncthreads();
    }
    int run = partl[t] - s;                // exclusive prefix of this chunk
    int* c = cums + img * NP;
#pragma unroll
    for (int j = 0; j < 32; ++j) { run += f[j]; c[base + j] = run; }
  }
  cg::this_grid().sync();                  // root[] and cums[] globally visible
  // ---- phase L: labels
  if (gid < IMGS * NP) {
    int img = gid / NP;
    int lab = cums[img * NP + root[gid]] - 1;
    out[gid] = (lab < MAXSEG - 1) ? lab : (MAXSEG - 1);
  }
}

extern "C" void kernel_launch(void* const* d_in, const int* in_sizes, int n_in,
                              void* d_out, int out_size, void* d_ws, size_t ws_size,
                              hipStream_t stream) {
  const float* x = (const float*)d_in[0];
  int* out = (int*)d_out;
  char* ws = (char*)d_ws;

  // workspace layout (~1.70 MB).
  // part (4 x IMGS*NP floats = 524288 B) aliases bufL — bufL dead after blur.
  // pkeys (2 x IMGS*NP u64 = 524288 B) aliases the same region — part dead
  // after k_densmerge; k_par writes pkeys after that (in-stream order).
  float4* pf   = (float4*)(ws);                         // 2*24576*16 = 786432
  float4* bufL = (float4*)(ws + 786432);                // 524288 (lab output)
  float* part  = (float*)(ws + 786432);                 // alias bufL, 524288
  unsigned long long* pkeys = (unsigned long long*)(ws + 786432);  // alias, 524288
  int* parent  = (int*)(ws + 1310720);                  // 131072
  int* root    = (int*)(ws + 1441792);                  // 131072
  int* cums    = (int*)(ws + 1572864);                  // 131072

  const int total = IMGS * NP;                          // 32768

  {
    void* a[] = { (void*)&x, (void*)&pf, (void*)&bufL };
    hipLaunchCooperativeKernel((const void*)k_prepblur, dim3(IMGS * H), dim3(384),
                               a, 0, stream);
  }
  k_dens<<<1024, 512, 0, stream>>>(pf, part);
  k_densmerge<<<total / 256, 256, 0, stream>>>(part, pf);
  k_par<<<1024, 512, 0, stream>>>(pf, pkeys);
  {
    void* a[] = { (void*)&pkeys, (void*)&parent, (void*)&root, (void*)&cums,
                  (void*)&out };
    hipLaunchCooperativeKernel((const void*)k_mrs, dim3(256), dim3(512),
                               a, 0, stream);
  }
}

// Round 16
// 153.107 us; speedup vs baseline: 1.6682x; 1.6682x over previous
//
#include <hip/hip_runtime.h>
#include <math.h>

static constexpr int IMGS = 2;
static constexpr int H = 128, W = 128;
static constexpr int NP = H * W;           // 16384
static constexpr int KWIN = 30;            // quickshift window radius (ceil(3*10))
static constexpr int PR = 20;              // parent prune radius: dr^2+dc^2>400 can't win (MAX_DIST=20)
static constexpr int GR = 20;              // gaussian radius int(4*5+0.5)
static constexpr float INV = 0.005f;       // 0.5 / (10*10)
static constexpr int MAXSEG = 40;

// padded feature layout: row stride 192 float4, cols [30,158) hold the image.
// float4 = (L, a, b, dens); pads = (1e6,1e6,1e6,-inf).
static constexpr int PSTR = 192;
static constexpr int PIMG = H * PSTR;      // 24576 float4 per image
static constexpr int NSEG = 64 + 2 * PR;   // 104 staged float4 per k_par row

typedef float f32x2 __attribute__((ext_vector_type(2)));

// ---------------- prep: pf sentinel fill + rgb2lab into bufL -------------------
__global__ void k_prep(const float* __restrict__ x, float4* __restrict__ pf,
                       float4* __restrict__ bufL) {
#pragma clang fp contract(off)
  int i = blockIdx.x * blockDim.x + threadIdx.x;
  if (i < IMGS * PIMG) pf[i] = make_float4(1e6f, 1e6f, 1e6f, -__builtin_inff());
  if (i >= IMGS * NP) return;
  int img = i / NP, p = i % NP;
  const float* base = x + img * 3 * NP;
  float rgb[3] = { base[p], base[NP + p], base[2 * NP + p] };
  float lin[3];
  for (int c = 0; c < 3; ++c) {
    float v = rgb[c];
    lin[c] = (v > 0.04045f) ? powf((v + 0.055f) / 1.055f, 2.4f) : (v / 12.92f);
  }
  const float M[3][3] = {{0.412453f, 0.357580f, 0.180423f},
                         {0.212671f, 0.715160f, 0.072169f},
                         {0.019334f, 0.119193f, 0.950227f}};
  const float wp[3] = {0.95047f, 1.0f, 1.08883f};
  float f[3];
  for (int j = 0; j < 3; ++j) {
    float s = lin[0] * M[j][0];
    s = s + lin[1] * M[j][1];
    s = s + lin[2] * M[j][2];
    float xyz = s / wp[j];
    f[j] = (xyz > 0.008856f) ? cbrtf(fmaxf(xyz, 1e-8f))
                             : (7.787f * xyz + (float)(16.0 / 116.0));
  }
  float L = 116.0f * f[1] - 16.0f;
  float a = 500.0f * (f[0] - f[1]);
  float b = 200.0f * (f[1] - f[2]);
  bufL[i] = make_float4(L, a, b, 0.0f);
}

// ---------------- fused separable gaussian (V then H), symmetric pad -----------
__global__ __launch_bounds__(384)
void k_blur(const float4* __restrict__ bufL, float4* __restrict__ pf) {
#pragma clang fp contract(off)
  __shared__ float w[2 * GR + 1];
  __shared__ float mid[3][128];
  if (threadIdx.x == 0) {
    double k[2 * GR + 1];
    double s = 0.0;
    for (int i = -GR; i <= GR; ++i) {
      double t = (double)i / 5.0;
      double v = exp(-0.5 * t * t);
      k[i + GR] = v;
      s += v;
    }
    for (int i = 0; i < 2 * GR + 1; ++i) w[i] = (float)(k[i] / s);
  }
  __syncthreads();
  int tid = threadIdx.x;
  int c = tid >> 7;                         // 0..2
  int xx = tid & 127;
  int b = blockIdx.x;                       // img*128 + y
  int y = b & 127, img = b >> 7;
  const float* base = (const float*)(bufL + img * NP);
  float a = 0.0f;
  for (int t = 0; t <= 2 * GR; ++t) {
    int yy = y - GR + t;
    if (yy < 0) yy = -yy - 1;
    if (yy >= H) yy = 2 * H - 1 - yy;
    a = a + w[t] * base[(yy * W + xx) * 4 + c];
  }
  mid[c][xx] = a;
  __syncthreads();
  float o = 0.0f;
  for (int t = 0; t <= 2 * GR; ++t) {
    int xq = xx - GR + t;
    if (xq < 0) xq = -xq - 1;
    if (xq >= W) xq = 2 * W - 1 - xq;
    o = o + w[t] * mid[c][xq];
  }
  ((float*)(pf + img * PIMG + y * PSTR + xx + KWIN))[c] = o;  // 4B store, no race
}

// ---------------- density: 2-center rows x 4-way row-split, barrier-free -------
// (validated best: 50.4us @ R11/R14. 4-center (R12) spills — do not revisit.
// Density keeps the FULL 61x61 window: no distance cutoff, far terms ~exp(-2).)
__device__ inline void dens_row2(const float4* __restrict__ grow,
                                 float4 fc0, float4 fc1,
                                 float sprf0, float sprf1, int lane,
                                 float& acc0, float& acc1) {
#pragma clang fp contract(off)
  const f32x2 nInv = { -INV, -INV };
#pragma unroll
  for (int d0 = 0; d0 + 1 < 61; d0 += 2) {
    float4 nb0 = grow[lane + d0];
    float4 nb1 = grow[lane + d0 + 1];
    float c0 = (float)((d0 - KWIN) * (d0 - KWIN));
    float c1 = (float)((d0 + 1 - KWIN) * (d0 + 1 - KWIN));
    // center 0
    f32x2 dx0 = { fc0.x - nb0.x, fc0.x - nb1.x };
    f32x2 dy0 = { fc0.y - nb0.y, fc0.y - nb1.y };
    f32x2 dz0 = { fc0.z - nb0.z, fc0.z - nb1.z };
    f32x2 dd0 = (dx0 * dx0 + dy0 * dy0) + dz0 * dz0;
    f32x2 sp0 = { sprf0 + c0, sprf0 + c1 };   // exact: ints < 2^11 (or inf)
    dd0 = dd0 + sp0;
    f32x2 e0 = dd0 * nInv;                    // bit == -(d*INV)
    acc0 = acc0 + __expf(e0.x);               // in-order within row
    acc0 = acc0 + __expf(e0.y);
    // center 1 (same loaded neighbors)
    f32x2 dx1 = { fc1.x - nb0.x, fc1.x - nb1.x };
    f32x2 dy1 = { fc1.y - nb0.y, fc1.y - nb1.y };
    f32x2 dz1 = { fc1.z - nb0.z, fc1.z - nb1.z };
    f32x2 dd1 = (dx1 * dx1 + dy1 * dy1) + dz1 * dz1;
    f32x2 sp1 = { sprf1 + c0, sprf1 + c1 };
    dd1 = dd1 + sp1;
    f32x2 e1 = dd1 * nInv;
    acc1 = acc1 + __expf(e1.x);
    acc1 = acc1 + __expf(e1.y);
  }
  {                                           // dc = 60 tail, both centers
    float4 nb = grow[lane + 60];
    float ct = (float)((60 - KWIN) * (60 - KWIN));
    float a0 = fc0.x - nb.x, a1 = fc0.y - nb.y, a2 = fc0.z - nb.z;
    float d0 = (a0 * a0 + a1 * a1) + a2 * a2;
    d0 = d0 + (sprf0 + ct);
    acc0 = acc0 + __expf(-d0 * INV);
    float b0 = fc1.x - nb.x, b1 = fc1.y - nb.y, b2 = fc1.z - nb.z;
    float d1 = (b0 * b0 + b1 * b1) + b2 * b2;
    d1 = d1 + (sprf1 + ct);
    acc1 = acc1 + __expf(-d1 * INV);
  }
}

__global__ __launch_bounds__(512, 4)
void k_dens(const float4* __restrict__ pf, float* __restrict__ part) {
#pragma clang fp contract(off)
  __shared__ float pbuf[8][2][64];
  int tid = threadIdx.x;
  int lane = tid & 63;
  int wave = tid >> 6;
  int b = blockIdx.x;                      // 1024: img*512 + ygrp*8 + tile*4 + q
  int q = b & 3, tile = (b >> 2) & 1, ygrp = (b >> 3) & 63, img = b >> 9;
  int y0 = ygrp * 2, y1 = y0 + 1;
  int x0 = tile * 64;
  const float4* fimg = pf + img * PIMG;
  float4 fc0 = fimg[y0 * PSTR + x0 + lane + KWIN];
  float4 fc1 = fimg[y1 * PSTR + x0 + lane + KWIN];
  int lo = y0 - KWIN; if (lo < 0) lo = 0;
  int hi = y1 + KWIN; if (hi > H - 1) hi = H - 1;
  int nr = hi - lo + 1;                    // 32..62 union rows
  int c = q * 8 + wave;                    // 0..31 ascending row chunks
  int base = nr >> 5, rem = nr & 31;       // base>=1, so all chunks nonempty
  int cnt = base + (c < rem ? 1 : 0);
  int start = lo + c * base + (c < rem ? c : rem);
  float acc0 = 0.0f, acc1 = 0.0f;
  for (int r = 0; r < cnt; ++r) {
    int ny = start + r;
    int dr0 = ny - y0, dr1 = ny - y1;
    // wave-uniform activity guards; inactive => sprf=inf => exact +0.0 terms
    float s0 = (ny <= y0 + KWIN) ? (float)(dr0 * dr0) : __builtin_inff();
    float s1 = (ny >= y1 - KWIN) ? (float)(dr1 * dr1) : __builtin_inff();
    const float4* grow = fimg + ny * PSTR + x0;
    dens_row2(grow, fc0, fc1, s0, s1, lane, acc0, acc1);
  }
  pbuf[wave][0][lane] = acc0;              // publish row-chunk partials
  pbuf[wave][1][lane] = acc1;
  __syncthreads();
  if (wave < 2) {                          // wave w folds center row y0+w
    float a = pbuf[0][wave][lane];
#pragma unroll
    for (int w = 1; w < 8; ++w) a = a + pbuf[w][wave][lane];
    part[q * (IMGS * NP) + img * NP + (y0 + wave) * W + x0 + lane] = a;
  }
}

// ---------------- fold the 4 row-quarter partials into pf.w --------------------
// Ascending-q = ascending-row order, left-to-right: bitwise-deterministic.
__global__ void k_densmerge(const float* __restrict__ part, float4* __restrict__ pf) {
#pragma clang fp contract(off)
  int i = blockIdx.x * blockDim.x + threadIdx.x;
  if (i >= IMGS * NP) return;
  int img = i / NP, p = i % NP, y = p >> 7, x = p & 127;
  float s = ((part[i] + part[IMGS * NP + i]) + part[2 * IMGS * NP + i])
            + part[3 * IMGS * NP + i];
  pf[img * PIMG + y * PSTR + x + KWIN].w = s;
}

// ---------------- parent: +-20 pruned window, half-split, AoS b128, pairs ------
// (R11, validated: semantic prune — MAX_DIST=20 means dr^2+dc^2>400 candidates
// can never be sub-threshold winners; 41x41 window = 45% of the work.)
template<int DB, int DE>
__device__ inline void par_pairs(const float4* __restrict__ rb,
                                 int lane, f32x2 fcx, f32x2 fcy, f32x2 fcz,
                                 float dcen, float sprf, int qbase,
                                 float& bestd, int& bestp) {
#pragma clang fp contract(off)
#pragma unroll
  for (int d0 = DB; d0 + 1 < DE; d0 += 2) {
    int i0 = lane + d0;
    float4 nb0 = rb[i0];
    float4 nb1 = rb[i0 + 1];
    f32x2 nx = { nb0.x, nb1.x };
    f32x2 nv = { nb0.y, nb1.y };
    f32x2 nz = { nb0.z, nb1.z };
    f32x2 nw = { nb0.w, nb1.w };
    f32x2 dx = fcx - nx, dy = fcy - nv, dz = fcz - nz;
    f32x2 dd = (dx * dx + dy * dy) + dz * dz;
    f32x2 sp = { sprf + (float)((d0 - PR) * (d0 - PR)),
                 sprf + (float)((d0 + 1 - PR) * (d0 + 1 - PR)) };
    dd = dd + sp;                          // exact (ints < 2^11)
    int b0 = (nw.x > dcen) & (dd.x < bestd);
    bestd = b0 ? dd.x : bestd;
    bestp = b0 ? (qbase + d0 - PR) : bestp;
    int b1 = (nw.y > dcen) & (dd.y < bestd);
    bestd = b1 ? dd.y : bestd;
    bestp = b1 ? (qbase + d0 + 1 - PR) : bestp;
  }
  if constexpr ((DE - DB) & 1) {           // scalar tail
    constexpr int dcu = DE - 1;
    float4 nb = rb[lane + dcu];
    float nd = nb.w;
    float d0 = fcx.x - nb.x, d1 = fcy.x - nb.y, d2 = fcz.x - nb.z;
    float d = (d0 * d0 + d1 * d1) + d2 * d2;
    d = d + (sprf + (float)((dcu - PR) * (dcu - PR)));
    int bt = (nd > dcen) & (d < bestd);
    bestd = bt ? d : bestd;
    bestp = bt ? (qbase + dcu - PR) : bestp;
  }
}

template<int DB, int DE>
__device__ inline void par_two_rows(const float4* __restrict__ bufA,
                                    const float4* __restrict__ bufB,
                                    int lane, f32x2 fcx, f32x2 fcy, f32x2 fcz,
                                    float dcen, int y, int x,
                                    int nyA, bool haveB,
                                    float& bestd, int& bestp) {
#pragma clang fp contract(off)
  int drA = nyA - y;
  par_pairs<DB, DE>(bufA, lane, fcx, fcy, fcz, dcen,
                    (float)(drA * drA), nyA * W + x, bestd, bestp);
  if (haveB) {
    int drB = nyA + 1 - y;
    par_pairs<DB, DE>(bufB, lane, fcx, fcy, fcz, dcen,
                      (float)(drB * drB), (nyA + 1) * W + x, bestd, bestp);
  }
}

__global__ __launch_bounds__(512, 4)
void k_par(const float4* __restrict__ pf, unsigned long long* __restrict__ pkeys) {
#pragma clang fp contract(off)
  __shared__ float4 aos[2][2][NSEG];       // [buf][row-of-pair][col]
  __shared__ unsigned long long m_k[8][64];
  int tid = threadIdx.x, lane = tid & 63, wave = tid >> 6;
  int b = blockIdx.x;                      // img*512 + y*4 + tile*2 + half
  int half = b & 1, tile = (b >> 1) & 1, y = (b >> 2) & 127, img = b >> 9;
  int x0 = tile * 64, x = x0 + lane;
  const float4* fimg = pf + img * PIMG;
  float4 fc = fimg[y * PSTR + x + KWIN];
  float dcen = fc.w;
  f32x2 fcx = { fc.x, fc.x }, fcy = { fc.y, fc.y }, fcz = { fc.z, fc.z };
  int ny0 = y - PR; if (ny0 < 0) ny0 = 0;
  int ny1 = y + PR; if (ny1 > H - 1) ny1 = H - 1;
  int nr = ny1 - ny0 + 1;                  // 21..41
  int h0 = nr >> 1;                        // rows in half 0
  int hb = half ? (ny0 + h0) : ny0;
  int he = half ? (ny1 + 1) : (ny0 + h0);
  int cnt = he - hb;                       // >= 10
  // pair staging: 2 rows x NSEG float4 = 2*208 float2; threads 0..207 stage
  // row A (float2 index sidx), threads 256..463 stage row B.
  int rsel = tid >> 8;                     // 0..1
  int sidx = tid & 255;                    // float2 index within row
  const int segoff = x0 + (KWIN - PR);     // staged cols = x0-PR .. x0+63+PR
  {
    int rA = hb;
    int rB = (hb + 1 < he) ? hb + 1 : hb;  // clamp (unused if no row B)
    int rr = rsel ? rB : rA;
    if (sidx < NSEG * 2) {
      float2 v = *(const float2*)(((const float*)(fimg + rr * PSTR + segoff)) + sidx * 2);
      *(float2*)(((float*)&aos[0][rsel][0]) + sidx * 2) = v;
    }
  }
  __syncthreads();
  float bestd = __builtin_inff();
  int bestp = y * W + x;
  int npairs = (cnt + 1) >> 1;
  for (int p = 0; p < npairs; ++p) {
    int kb = p & 1;
    float2 pv;
    bool pre = (p + 1 < npairs);
    if (pre) {                             // issue next-pair global loads early
      int nA = hb + 2 * (p + 1);
      int nB = (nA + 1 < he) ? nA + 1 : nA;
      int pr_row = rsel ? nB : nA;
      if (sidx < NSEG * 2)
        pv = *(const float2*)(((const float*)(fimg + pr_row * PSTR + segoff)) + sidx * 2);
    }
    int nyA = hb + 2 * p;
    bool haveB = (nyA + 1 < he);           // wave-uniform
    const float4* bufA = &aos[kb][0][0];
    const float4* bufB = &aos[kb][1][0];
    if      (wave == 0) par_two_rows< 0,  6>(bufA, bufB, lane, fcx, fcy, fcz, dcen, y, x, nyA, haveB, bestd, bestp);
    else if (wave == 1) par_two_rows< 6, 11>(bufA, bufB, lane, fcx, fcy, fcz, dcen, y, x, nyA, haveB, bestd, bestp);
    else if (wave == 2) par_two_rows<11, 16>(bufA, bufB, lane, fcx, fcy, fcz, dcen, y, x, nyA, haveB, bestd, bestp);
    else if (wave == 3) par_two_rows<16, 21>(bufA, bufB, lane, fcx, fcy, fcz, dcen, y, x, nyA, haveB, bestd, bestp);
    else if (wave == 4) par_two_rows<21, 26>(bufA, bufB, lane, fcx, fcy, fcz, dcen, y, x, nyA, haveB, bestd, bestp);
    else if (wave == 5) par_two_rows<26, 31>(bufA, bufB, lane, fcx, fcy, fcz, dcen, y, x, nyA, haveB, bestd, bestp);
    else if (wave == 6) par_two_rows<31, 36>(bufA, bufB, lane, fcx, fcy, fcz, dcen, y, x, nyA, haveB, bestd, bestp);
    else                par_two_rows<36, 41>(bufA, bufB, lane, fcx, fcy, fcz, dcen, y, x, nyA, haveB, bestd, bestp);
    if (pre && sidx < NSEG * 2)            // write other buffer: no race now
      *(float2*)(((float*)&aos[kb ^ 1][rsel][0]) + sidx * 2) = pv;
    __syncthreads();                       // publish next pair
  }
  // pack (d, q): inf (no candidate) sorts above all finite d
  m_k[wave][lane] =
      ((unsigned long long)__float_as_uint(bestd) << 32) | (unsigned)bestp;
  __syncthreads();
  if (wave == 0) {
    unsigned long long k = m_k[0][lane];
#pragma unroll
    for (int w = 1; w < 8; ++w) {
      unsigned long long kw = m_k[w][lane];
      k = (kw < k) ? kw : k;
    }
    pkeys[half * (IMGS * NP) + img * NP + y * W + x] = k;
  }
}

// ---------------- merge halves -> parent ---------------------------------------
__global__ void k_merge(const unsigned long long* __restrict__ pkeys,
                        int* __restrict__ parent) {
  int i = blockIdx.x * blockDim.x + threadIdx.x;
  if (i >= IMGS * NP) return;
  unsigned long long k0 = pkeys[i], k1 = pkeys[IMGS * NP + i];
  unsigned long long k = (k0 < k1) ? k0 : k1;
  float bd = __uint_as_float((unsigned)(k >> 32));
  int p = i % NP;
  parent[i] = (bd > 400.0f) ? p : (int)(k & 0xffffffffu);  // sqrt(d) > max_dist
}

// ---------------- root find via path-halving union-find (R31) ------------------
// Replaces the serial chase (R15's counters: the chase was ~55us at <1% VALU —
// latency-bound). Path halving: par[v] = par[par[v]] while walking. Races are
// BENIGN: every write replaces a parent with a strict ancestor (valid, monotone
// toward the root; forest is acyclic because density strictly increases along
// chains), so concurrent threads cooperatively compress shared paths — per-
// thread steps collapse to ~O(log). The returned root is the chain's unique
// fixed point => root[] bit-identical to the serial chase. Root flags
// (parent[i]==i) are PRESERVED: roots are never rewritten, and a non-root's
// new parent is an ancestor != itself (acyclic), so k_scanlabel is unchanged.
__global__ void k_root(int* __restrict__ parent, int* __restrict__ root) {
  int i = blockIdx.x * blockDim.x + threadIdx.x;
  if (i >= IMGS * NP) return;
  int img = i / NP, p = i % NP;
  int* par = parent + img * NP;
  int v = p;
  int pr = par[v];
  int gp = par[pr];
  while (pr != gp) {
    par[v] = gp;                           // halve (benign race: gp = ancestor)
    v = gp;
    pr = par[v];
    gp = par[pr];
  }
  root[i] = pr;
}

// ---------------- scan of root flags + final labels (fused, coalesced) ---------
__global__ __launch_bounds__(1024)
void k_scanlabel(const int* __restrict__ parent, const int* __restrict__ root,
                 int* __restrict__ cums, int* __restrict__ out) {
  __shared__ int part[1024];
  int img = blockIdx.x;
  int t = threadIdx.x;                     // 1024 threads x 16 elements
  const int* par = parent + img * NP;
  int base = t * 16;
  int f[16];
  const int4* p4 = (const int4*)(par + base);
#pragma unroll
  for (int j = 0; j < 4; ++j) {
    int4 v = p4[j];
    f[4 * j + 0] = (v.x == base + 4 * j + 0);
    f[4 * j + 1] = (v.y == base + 4 * j + 1);
    f[4 * j + 2] = (v.z == base + 4 * j + 2);
    f[4 * j + 3] = (v.w == base + 4 * j + 3);
  }
  int s = 0;
#pragma unroll
  for (int j = 0; j < 16; ++j) s += f[j];
  part[t] = s;
  __syncthreads();
  for (int off = 1; off < 1024; off <<= 1) {
    int add = (t >= off) ? part[t - off] : 0;
    __syncthreads();
    part[t] += add;
    __syncthreads();
  }
  int run = part[t] - s;                   // exclusive prefix of this chunk
  int* c = cums + img * NP;
#pragma unroll
  for (int j = 0; j < 16; ++j) { run += f[j]; c[base + j] = run; }
  __threadfence_block();
  __syncthreads();                         // block-visible global writes
  const int* rimg = root + img * NP;
  int* oimg = out + img * NP;
  for (int j = t; j < NP; j += 1024) {
    int lab = c[rimg[j]] - 1;
    oimg[j] = (lab < MAXSEG - 1) ? lab : (MAXSEG - 1);
  }
}

extern "C" void kernel_launch(void* const* d_in, const int* in_sizes, int n_in,
                              void* d_out, int out_size, void* d_ws, size_t ws_size,
                              hipStream_t stream) {
  const float* x = (const float*)d_in[0];
  int* out = (int*)d_out;
  char* ws = (char*)d_ws;

  // workspace layout (~1.70 MB).
  // part (4 x IMGS*NP floats = 524288 B) aliases bufL — bufL dead after k_blur.
  // pkeys (2 x IMGS*NP u64 = 524288 B) aliases the same region — part dead
  // after k_densmerge; k_par writes pkeys after that (in-stream order).
  float4* pf   = (float4*)(ws);                         // 2*24576*16 = 786432
  float4* bufL = (float4*)(ws + 786432);                // 524288 (lab output)
  float* part  = (float*)(ws + 786432);                 // alias bufL, 524288
  unsigned long long* pkeys = (unsigned long long*)(ws + 786432);  // alias, 524288
  int* parent  = (int*)(ws + 1310720);                  // 131072
  int* root    = (int*)(ws + 1441792);                  // 131072
  int* cums    = (int*)(ws + 1572864);                  // 131072

  const int total = IMGS * NP;                          // 32768
  const int ptotal = IMGS * PIMG;                       // 49152

  k_prep<<<(ptotal + 255) / 256, 256, 0, stream>>>(x, pf, bufL);
  k_blur<<<IMGS * H, 384, 0, stream>>>(bufL, pf);
  k_dens<<<1024, 512, 0, stream>>>(pf, part);
  k_densmerge<<<total / 256, 256, 0, stream>>>(part, pf);
  k_par<<<1024, 512, 0, stream>>>(pf, pkeys);
  k_merge<<<total / 256, 256, 0, stream>>>(pkeys, parent);
  k_root<<<total / 256, 256, 0, stream>>>(parent, root);
  k_scanlabel<<<IMGS, 1024, 0, stream>>>(parent, root, cums, out);
}

// Round 17
// 150.512 us; speedup vs baseline: 1.6970x; 1.0172x over previous
//
#include <hip/hip_runtime.h>
#include <math.h>

static constexpr int IMGS = 2;
static constexpr int H = 128, W = 128;
static constexpr int NP = H * W;           // 16384
static constexpr int KWIN = 30;            // quickshift window radius (ceil(3*10))
static constexpr int PR = 20;              // parent prune radius: dr^2+dc^2>400 can't win (MAX_DIST=20)
static constexpr int GR = 20;              // gaussian radius int(4*5+0.5)
static constexpr float INV = 0.005f;       // 0.5 / (10*10)
static constexpr int MAXSEG = 40;

// padded feature layout: row stride 192 float4, cols [30,158) hold the image.
// float4 = (L, a, b, dens); pads = (1e6,1e6,1e6,-inf).
static constexpr int PSTR = 192;
static constexpr int PIMG = H * PSTR;      // 24576 float4 per image
static constexpr int NSEG = 64 + 2 * PR;   // 104 staged float4 per k_par row
static constexpr int NSEGD = 64 + 2 * KWIN; // 124 staged float4 per k_dens row

typedef float f32x2 __attribute__((ext_vector_type(2)));

// ---------------- prep: pf sentinel fill + rgb2lab into bufL -------------------
__global__ void k_prep(const float* __restrict__ x, float4* __restrict__ pf,
                       float4* __restrict__ bufL) {
#pragma clang fp contract(off)
  int i = blockIdx.x * blockDim.x + threadIdx.x;
  if (i < IMGS * PIMG) pf[i] = make_float4(1e6f, 1e6f, 1e6f, -__builtin_inff());
  if (i >= IMGS * NP) return;
  int img = i / NP, p = i % NP;
  const float* base = x + img * 3 * NP;
  float rgb[3] = { base[p], base[NP + p], base[2 * NP + p] };
  float lin[3];
  for (int c = 0; c < 3; ++c) {
    float v = rgb[c];
    lin[c] = (v > 0.04045f) ? powf((v + 0.055f) / 1.055f, 2.4f) : (v / 12.92f);
  }
  const float M[3][3] = {{0.412453f, 0.357580f, 0.180423f},
                         {0.212671f, 0.715160f, 0.072169f},
                         {0.019334f, 0.119193f, 0.950227f}};
  const float wp[3] = {0.95047f, 1.0f, 1.08883f};
  float f[3];
  for (int j = 0; j < 3; ++j) {
    float s = lin[0] * M[j][0];
    s = s + lin[1] * M[j][1];
    s = s + lin[2] * M[j][2];
    float xyz = s / wp[j];
    f[j] = (xyz > 0.008856f) ? cbrtf(fmaxf(xyz, 1e-8f))
                             : (7.787f * xyz + (float)(16.0 / 116.0));
  }
  float L = 116.0f * f[1] - 16.0f;
  float a = 500.0f * (f[0] - f[1]);
  float b = 200.0f * (f[1] - f[2]);
  bufL[i] = make_float4(L, a, b, 0.0f);
}

// ---------------- fused separable gaussian (V then H), symmetric pad -----------
__global__ __launch_bounds__(384)
void k_blur(const float4* __restrict__ bufL, float4* __restrict__ pf) {
#pragma clang fp contract(off)
  __shared__ float w[2 * GR + 1];
  __shared__ float mid[3][128];
  if (threadIdx.x == 0) {
    double k[2 * GR + 1];
    double s = 0.0;
    for (int i = -GR; i <= GR; ++i) {
      double t = (double)i / 5.0;
      double v = exp(-0.5 * t * t);
      k[i + GR] = v;
      s += v;
    }
    for (int i = 0; i < 2 * GR + 1; ++i) w[i] = (float)(k[i] / s);
  }
  __syncthreads();
  int tid = threadIdx.x;
  int c = tid >> 7;                         // 0..2
  int xx = tid & 127;
  int b = blockIdx.x;                       // img*128 + y
  int y = b & 127, img = b >> 7;
  const float* base = (const float*)(bufL + img * NP);
  float a = 0.0f;
  for (int t = 0; t <= 2 * GR; ++t) {
    int yy = y - GR + t;
    if (yy < 0) yy = -yy - 1;
    if (yy >= H) yy = 2 * H - 1 - yy;
    a = a + w[t] * base[(yy * W + xx) * 4 + c];
  }
  mid[c][xx] = a;
  __syncthreads();
  float o = 0.0f;
  for (int t = 0; t <= 2 * GR; ++t) {
    int xq = xx - GR + t;
    if (xq < 0) xq = -xq - 1;
    if (xq >= W) xq = 2 * W - 1 - xq;
    o = o + w[t] * mid[c][xq];
  }
  ((float*)(pf + img * PIMG + y * PSTR + xx + KWIN))[c] = o;  // 4B store, no race
}

// ---------------- density: LDS pair-staged, dc-stripe waves (R32) --------------
// R16's k_dens was L1-pipe-bound: 61 overlapping shifted L1 wave-loads per row
// (~38us/CU of L1 time vs 28us VALU). This ports k_par's PROVEN pair-staging
// structure (conflicts 0, clean VGPR): stage row pairs (124-float4 segment)
// into LDS once, 8 waves partition the 61 dc columns into stripes, each wave
// accumulates both centers' stripe partials in registers; ONE barrier per row
// pair. Fold: wave-ascending within block, then ascending q planes (densmerge)
// — dc-stripe reassociation is the class that passed R2 + every round since
// (absmax 0). Per-term IEEE ops identical (pk ops, d*(-INV), __expf; pad
// sentinels / inactive-row sprf=inf => exact +0.0 terms).
template<int DB, int DE>
__device__ inline void dens_stripe2(const float4* __restrict__ rb,
                                    float4 fc0, float4 fc1,
                                    float s0, float s1, int lane,
                                    float& acc0, float& acc1) {
#pragma clang fp contract(off)
  const f32x2 nInv = { -INV, -INV };
#pragma unroll
  for (int d0 = DB; d0 + 1 < DE; d0 += 2) {
    float4 nb0 = rb[lane + d0];
    float4 nb1 = rb[lane + d0 + 1];
    float c0 = (float)((d0 - KWIN) * (d0 - KWIN));
    float c1 = (float)((d0 + 1 - KWIN) * (d0 + 1 - KWIN));
    // center 0
    f32x2 dx0 = { fc0.x - nb0.x, fc0.x - nb1.x };
    f32x2 dy0 = { fc0.y - nb0.y, fc0.y - nb1.y };
    f32x2 dz0 = { fc0.z - nb0.z, fc0.z - nb1.z };
    f32x2 dd0 = (dx0 * dx0 + dy0 * dy0) + dz0 * dz0;
    f32x2 sp0 = { s0 + c0, s0 + c1 };     // exact: ints < 2^11 (or inf)
    dd0 = dd0 + sp0;
    f32x2 e0 = dd0 * nInv;                // bit == -(d*INV)
    acc0 = acc0 + __expf(e0.x);           // in-order within stripe
    acc0 = acc0 + __expf(e0.y);
    // center 1 (same staged neighbors)
    f32x2 dx1 = { fc1.x - nb0.x, fc1.x - nb1.x };
    f32x2 dy1 = { fc1.y - nb0.y, fc1.y - nb1.y };
    f32x2 dz1 = { fc1.z - nb0.z, fc1.z - nb1.z };
    f32x2 dd1 = (dx1 * dx1 + dy1 * dy1) + dz1 * dz1;
    f32x2 sp1 = { s1 + c0, s1 + c1 };
    dd1 = dd1 + sp1;
    f32x2 e1 = dd1 * nInv;
    acc1 = acc1 + __expf(e1.x);
    acc1 = acc1 + __expf(e1.y);
  }
  if constexpr ((DE - DB) & 1) {          // scalar tail
    constexpr int dcu = DE - 1;
    float4 nb = rb[lane + dcu];
    float ct = (float)((dcu - KWIN) * (dcu - KWIN));
    float a0 = fc0.x - nb.x, a1 = fc0.y - nb.y, a2 = fc0.z - nb.z;
    float d0 = (a0 * a0 + a1 * a1) + a2 * a2;
    d0 = d0 + (s0 + ct);
    acc0 = acc0 + __expf(-d0 * INV);
    float b0 = fc1.x - nb.x, b1 = fc1.y - nb.y, b2 = fc1.z - nb.z;
    float d1 = (b0 * b0 + b1 * b1) + b2 * b2;
    d1 = d1 + (s1 + ct);
    acc1 = acc1 + __expf(-d1 * INV);
  }
}

template<int DB, int DE>
__device__ inline void dens_two_rows(const float4* __restrict__ bufA,
                                     const float4* __restrict__ bufB,
                                     float4 fc0, float4 fc1, int lane,
                                     int y0, int y1, int nyA, bool haveB,
                                     float& acc0, float& acc1) {
#pragma clang fp contract(off)
  {
    int dr0 = nyA - y0, dr1 = nyA - y1;
    float s0 = (nyA <= y0 + KWIN) ? (float)(dr0 * dr0) : __builtin_inff();
    float s1 = (nyA >= y1 - KWIN) ? (float)(dr1 * dr1) : __builtin_inff();
    dens_stripe2<DB, DE>(bufA, fc0, fc1, s0, s1, lane, acc0, acc1);
  }
  if (haveB) {
    int nyB = nyA + 1;
    int dr0 = nyB - y0, dr1 = nyB - y1;
    float s0 = (nyB <= y0 + KWIN) ? (float)(dr0 * dr0) : __builtin_inff();
    float s1 = (nyB >= y1 - KWIN) ? (float)(dr1 * dr1) : __builtin_inff();
    dens_stripe2<DB, DE>(bufB, fc0, fc1, s0, s1, lane, acc0, acc1);
  }
}

__global__ __launch_bounds__(512, 4)
void k_dens(const float4* __restrict__ pf, float* __restrict__ part) {
#pragma clang fp contract(off)
  __shared__ float4 aos[2][2][NSEGD];      // [buf][row-of-pair][col]
  __shared__ float pbuf[8][2][64];
  int tid = threadIdx.x;
  int lane = tid & 63;
  int wave = tid >> 6;
  int b = blockIdx.x;                      // 1024: img*512 + ygrp*8 + tile*4 + q
  int q = b & 3, tile = (b >> 2) & 1, ygrp = (b >> 3) & 63, img = b >> 9;
  int y0 = ygrp * 2, y1 = y0 + 1;
  int x0 = tile * 64;
  const float4* fimg = pf + img * PIMG;
  float4 fc0 = fimg[y0 * PSTR + x0 + lane + KWIN];
  float4 fc1 = fimg[y1 * PSTR + x0 + lane + KWIN];
  int lo = y0 - KWIN; if (lo < 0) lo = 0;
  int hi = y1 + KWIN; if (hi > H - 1) hi = H - 1;
  int nr = hi - lo + 1;                    // 32..62 union rows
  int base = nr >> 2, rem = nr & 3;        // quarter row chunks (base >= 8)
  int cnt = base + (q < rem ? 1 : 0);
  int start = lo + q * base + (q < rem ? q : rem);
  int end = start + cnt;
  // pair staging: 2 rows x NSEGD float4 = 2*248 float2; threads 0..247 stage
  // row A, threads 256..503 stage row B (mirrors k_par's proven pattern).
  int rsel = tid >> 8;                     // 0..1
  int sidx = tid & 255;                    // float2 index within row
  {
    int rA = start;
    int rB = (start + 1 < end) ? start + 1 : start;  // clamp (unused if !B)
    int rr = rsel ? rB : rA;
    if (sidx < NSEGD * 2) {
      float2 v = *(const float2*)(((const float*)(fimg + rr * PSTR + x0)) + sidx * 2);
      *(float2*)(((float*)&aos[0][rsel][0]) + sidx * 2) = v;
    }
  }
  __syncthreads();
  float acc0 = 0.0f, acc1 = 0.0f;
  int npairs = (cnt + 1) >> 1;
  for (int p = 0; p < npairs; ++p) {
    int kb = p & 1;
    float2 pv;
    bool pre = (p + 1 < npairs);
    if (pre) {                             // issue next-pair global loads early
      int nA = start + 2 * (p + 1);
      int nB = (nA + 1 < end) ? nA + 1 : nA;
      int pr_row = rsel ? nB : nA;
      if (sidx < NSEGD * 2)
        pv = *(const float2*)(((const float*)(fimg + pr_row * PSTR + x0)) + sidx * 2);
    }
    int nyA = start + 2 * p;
    bool haveB = (nyA + 1 < end);          // wave-uniform
    const float4* bufA = &aos[kb][0][0];
    const float4* bufB = &aos[kb][1][0];
    if      (wave == 0) dens_two_rows< 0,  8>(bufA, bufB, fc0, fc1, lane, y0, y1, nyA, haveB, acc0, acc1);
    else if (wave == 1) dens_two_rows< 8, 16>(bufA, bufB, fc0, fc1, lane, y0, y1, nyA, haveB, acc0, acc1);
    else if (wave == 2) dens_two_rows<16, 24>(bufA, bufB, fc0, fc1, lane, y0, y1, nyA, haveB, acc0, acc1);
    else if (wave == 3) dens_two_rows<24, 32>(bufA, bufB, fc0, fc1, lane, y0, y1, nyA, haveB, acc0, acc1);
    else if (wave == 4) dens_two_rows<32, 40>(bufA, bufB, fc0, fc1, lane, y0, y1, nyA, haveB, acc0, acc1);
    else if (wave == 5) dens_two_rows<40, 48>(bufA, bufB, fc0, fc1, lane, y0, y1, nyA, haveB, acc0, acc1);
    else if (wave == 6) dens_two_rows<48, 56>(bufA, bufB, fc0, fc1, lane, y0, y1, nyA, haveB, acc0, acc1);
    else                dens_two_rows<56, 61>(bufA, bufB, fc0, fc1, lane, y0, y1, nyA, haveB, acc0, acc1);
    if (pre && sidx < NSEGD * 2)           // write other buffer: no race now
      *(float2*)(((float*)&aos[kb ^ 1][rsel][0]) + sidx * 2) = pv;
    __syncthreads();                       // publish next pair
  }
  pbuf[wave][0][lane] = acc0;              // publish dc-stripe partials
  pbuf[wave][1][lane] = acc1;
  __syncthreads();
  if (wave < 2) {                          // wave w folds center row y0+w
    float a = pbuf[0][wave][lane];
#pragma unroll
    for (int w = 1; w < 8; ++w) a = a + pbuf[w][wave][lane];
    part[q * (IMGS * NP) + img * NP + (y0 + wave) * W + x0 + lane] = a;
  }
}

// ---------------- fold the 4 row-quarter partials into pf.w --------------------
// Ascending-q = ascending-row order, left-to-right: bitwise-deterministic.
__global__ void k_densmerge(const float* __restrict__ part, float4* __restrict__ pf) {
#pragma clang fp contract(off)
  int i = blockIdx.x * blockDim.x + threadIdx.x;
  if (i >= IMGS * NP) return;
  int img = i / NP, p = i % NP, y = p >> 7, x = p & 127;
  float s = ((part[i] + part[IMGS * NP + i]) + part[2 * IMGS * NP + i])
            + part[3 * IMGS * NP + i];
  pf[img * PIMG + y * PSTR + x + KWIN].w = s;
}

// ---------------- parent: +-20 pruned window, half-split, AoS b128, pairs ------
// (R11, validated: semantic prune — MAX_DIST=20 means dr^2+dc^2>400 candidates
// can never be sub-threshold winners; 41x41 window = 45% of the work.)
template<int DB, int DE>
__device__ inline void par_pairs(const float4* __restrict__ rb,
                                 int lane, f32x2 fcx, f32x2 fcy, f32x2 fcz,
                                 float dcen, float sprf, int qbase,
                                 float& bestd, int& bestp) {
#pragma clang fp contract(off)
#pragma unroll
  for (int d0 = DB; d0 + 1 < DE; d0 += 2) {
    int i0 = lane + d0;
    float4 nb0 = rb[i0];
    float4 nb1 = rb[i0 + 1];
    f32x2 nx = { nb0.x, nb1.x };
    f32x2 nv = { nb0.y, nb1.y };
    f32x2 nz = { nb0.z, nb1.z };
    f32x2 nw = { nb0.w, nb1.w };
    f32x2 dx = fcx - nx, dy = fcy - nv, dz = fcz - nz;
    f32x2 dd = (dx * dx + dy * dy) + dz * dz;
    f32x2 sp = { sprf + (float)((d0 - PR) * (d0 - PR)),
                 sprf + (float)((d0 + 1 - PR) * (d0 + 1 - PR)) };
    dd = dd + sp;                          // exact (ints < 2^11)
    int b0 = (nw.x > dcen) & (dd.x < bestd);
    bestd = b0 ? dd.x : bestd;
    bestp = b0 ? (qbase + d0 - PR) : bestp;
    int b1 = (nw.y > dcen) & (dd.y < bestd);
    bestd = b1 ? dd.y : bestd;
    bestp = b1 ? (qbase + d0 + 1 - PR) : bestp;
  }
  if constexpr ((DE - DB) & 1) {           // scalar tail
    constexpr int dcu = DE - 1;
    float4 nb = rb[lane + dcu];
    float nd = nb.w;
    float d0 = fcx.x - nb.x, d1 = fcy.x - nb.y, d2 = fcz.x - nb.z;
    float d = (d0 * d0 + d1 * d1) + d2 * d2;
    d = d + (sprf + (float)((dcu - PR) * (dcu - PR)));
    int bt = (nd > dcen) & (d < bestd);
    bestd = bt ? d : bestd;
    bestp = bt ? (qbase + dcu - PR) : bestp;
  }
}

template<int DB, int DE>
__device__ inline void par_two_rows(const float4* __restrict__ bufA,
                                    const float4* __restrict__ bufB,
                                    int lane, f32x2 fcx, f32x2 fcy, f32x2 fcz,
                                    float dcen, int y, int x,
                                    int nyA, bool haveB,
                                    float& bestd, int& bestp) {
#pragma clang fp contract(off)
  int drA = nyA - y;
  par_pairs<DB, DE>(bufA, lane, fcx, fcy, fcz, dcen,
                    (float)(drA * drA), nyA * W + x, bestd, bestp);
  if (haveB) {
    int drB = nyA + 1 - y;
    par_pairs<DB, DE>(bufB, lane, fcx, fcy, fcz, dcen,
                      (float)(drB * drB), (nyA + 1) * W + x, bestd, bestp);
  }
}

__global__ __launch_bounds__(512, 4)
void k_par(const float4* __restrict__ pf, unsigned long long* __restrict__ pkeys) {
#pragma clang fp contract(off)
  __shared__ float4 aos[2][2][NSEG];       // [buf][row-of-pair][col]
  __shared__ unsigned long long m_k[8][64];
  int tid = threadIdx.x, lane = tid & 63, wave = tid >> 6;
  int b = blockIdx.x;                      // img*512 + y*4 + tile*2 + half
  int half = b & 1, tile = (b >> 1) & 1, y = (b >> 2) & 127, img = b >> 9;
  int x0 = tile * 64, x = x0 + lane;
  const float4* fimg = pf + img * PIMG;
  float4 fc = fimg[y * PSTR + x + KWIN];
  float dcen = fc.w;
  f32x2 fcx = { fc.x, fc.x }, fcy = { fc.y, fc.y }, fcz = { fc.z, fc.z };
  int ny0 = y - PR; if (ny0 < 0) ny0 = 0;
  int ny1 = y + PR; if (ny1 > H - 1) ny1 = H - 1;
  int nr = ny1 - ny0 + 1;                  // 21..41
  int h0 = nr >> 1;                        // rows in half 0
  int hb = half ? (ny0 + h0) : ny0;
  int he = half ? (ny1 + 1) : (ny0 + h0);
  int cnt = he - hb;                       // >= 10
  // pair staging: 2 rows x NSEG float4 = 2*208 float2; threads 0..207 stage
  // row A (float2 index sidx), threads 256..463 stage row B.
  int rsel = tid >> 8;                     // 0..1
  int sidx = tid & 255;                    // float2 index within row
  const int segoff = x0 + (KWIN - PR);     // staged cols = x0-PR .. x0+63+PR
  {
    int rA = hb;
    int rB = (hb + 1 < he) ? hb + 1 : hb;  // clamp (unused if no row B)
    int rr = rsel ? rB : rA;
    if (sidx < NSEG * 2) {
      float2 v = *(const float2*)(((const float*)(fimg + rr * PSTR + segoff)) + sidx * 2);
      *(float2*)(((float*)&aos[0][rsel][0]) + sidx * 2) = v;
    }
  }
  __syncthreads();
  float bestd = __builtin_inff();
  int bestp = y * W + x;
  int npairs = (cnt + 1) >> 1;
  for (int p = 0; p < npairs; ++p) {
    int kb = p & 1;
    float2 pv;
    bool pre = (p + 1 < npairs);
    if (pre) {                             // issue next-pair global loads early
      int nA = hb + 2 * (p + 1);
      int nB = (nA + 1 < he) ? nA + 1 : nA;
      int pr_row = rsel ? nB : nA;
      if (sidx < NSEG * 2)
        pv = *(const float2*)(((const float*)(fimg + pr_row * PSTR + segoff)) + sidx * 2);
    }
    int nyA = hb + 2 * p;
    bool haveB = (nyA + 1 < he);           // wave-uniform
    const float4* bufA = &aos[kb][0][0];
    const float4* bufB = &aos[kb][1][0];
    if      (wave == 0) par_two_rows< 0,  6>(bufA, bufB, lane, fcx, fcy, fcz, dcen, y, x, nyA, haveB, bestd, bestp);
    else if (wave == 1) par_two_rows< 6, 11>(bufA, bufB, lane, fcx, fcy, fcz, dcen, y, x, nyA, haveB, bestd, bestp);
    else if (wave == 2) par_two_rows<11, 16>(bufA, bufB, lane, fcx, fcy, fcz, dcen, y, x, nyA, haveB, bestd, bestp);
    else if (wave == 3) par_two_rows<16, 21>(bufA, bufB, lane, fcx, fcy, fcz, dcen, y, x, nyA, haveB, bestd, bestp);
    else if (wave == 4) par_two_rows<21, 26>(bufA, bufB, lane, fcx, fcy, fcz, dcen, y, x, nyA, haveB, bestd, bestp);
    else if (wave == 5) par_two_rows<26, 31>(bufA, bufB, lane, fcx, fcy, fcz, dcen, y, x, nyA, haveB, bestd, bestp);
    else if (wave == 6) par_two_rows<31, 36>(bufA, bufB, lane, fcx, fcy, fcz, dcen, y, x, nyA, haveB, bestd, bestp);
    else                par_two_rows<36, 41>(bufA, bufB, lane, fcx, fcy, fcz, dcen, y, x, nyA, haveB, bestd, bestp);
    if (pre && sidx < NSEG * 2)            // write other buffer: no race now
      *(float2*)(((float*)&aos[kb ^ 1][rsel][0]) + sidx * 2) = pv;
    __syncthreads();                       // publish next pair
  }
  // pack (d, q): inf (no candidate) sorts above all finite d
  m_k[wave][lane] =
      ((unsigned long long)__float_as_uint(bestd) << 32) | (unsigned)bestp;
  __syncthreads();
  if (wave == 0) {
    unsigned long long k = m_k[0][lane];
#pragma unroll
    for (int w = 1; w < 8; ++w) {
      unsigned long long kw = m_k[w][lane];
      k = (kw < k) ? kw : k;
    }
    pkeys[half * (IMGS * NP) + img * NP + y * W + x] = k;
  }
}

// ---------------- merge halves -> parent ---------------------------------------
__global__ void k_merge(const unsigned long long* __restrict__ pkeys,
                        int* __restrict__ parent) {
  int i = blockIdx.x * blockDim.x + threadIdx.x;
  if (i >= IMGS * NP) return;
  unsigned long long k0 = pkeys[i], k1 = pkeys[IMGS * NP + i];
  unsigned long long k = (k0 < k1) ? k0 : k1;
  float bd = __uint_as_float((unsigned)(k >> 32));
  int p = i % NP;
  parent[i] = (bd > 400.0f) ? p : (int)(k & 0xffffffffu);  // sqrt(d) > max_dist
}

// ---------------- root find via path-halving union-find (R31, validated) -------
// Races are BENIGN: every write replaces a parent with a strict ancestor
// (forest acyclic: density strictly increases along chains), so concurrent
// threads cooperatively compress shared paths — ~O(log) steps each. root[] is
// the chain's unique fixed point => bit-identical to a serial chase. Root
// flags (parent[i]==i) preserved: roots never rewritten; a non-root's new
// parent is an ancestor != itself.
__global__ void k_root(int* __restrict__ parent, int* __restrict__ root) {
  int i = blockIdx.x * blockDim.x + threadIdx.x;
  if (i >= IMGS * NP) return;
  int img = i / NP, p = i % NP;
  int* par = parent + img * NP;
  int v = p;
  int pr = par[v];
  int gp = par[pr];
  while (pr != gp) {
    par[v] = gp;                           // halve (benign race: gp = ancestor)
    v = gp;
    pr = par[v];
    gp = par[pr];
  }
  root[i] = pr;
}

// ---------------- scan of root flags + final labels (fused, coalesced) ---------
__global__ __launch_bounds__(1024)
void k_scanlabel(const int* __restrict__ parent, const int* __restrict__ root,
                 int* __restrict__ cums, int* __restrict__ out) {
  __shared__ int part[1024];
  int img = blockIdx.x;
  int t = threadIdx.x;                     // 1024 threads x 16 elements
  const int* par = parent + img * NP;
  int base = t * 16;
  int f[16];
  const int4* p4 = (const int4*)(par + base);
#pragma unroll
  for (int j = 0; j < 4; ++j) {
    int4 v = p4[j];
    f[4 * j + 0] = (v.x == base + 4 * j + 0);
    f[4 * j + 1] = (v.y == base + 4 * j + 1);
    f[4 * j + 2] = (v.z == base + 4 * j + 2);
    f[4 * j + 3] = (v.w == base + 4 * j + 3);
  }
  int s = 0;
#pragma unroll
  for (int j = 0; j < 16; ++j) s += f[j];
  part[t] = s;
  __syncthreads();
  for (int off = 1; off < 1024; off <<= 1) {
    int add = (t >= off) ? part[t - off] : 0;
    __syncthreads();
    part[t] += add;
    __syncthreads();
  }
  int run = part[t] - s;                   // exclusive prefix of this chunk
  int* c = cums + img * NP;
#pragma unroll
  for (int j = 0; j < 16; ++j) { run += f[j]; c[base + j] = run; }
  __threadfence_block();
  __syncthreads();                         // block-visible global writes
  const int* rimg = root + img * NP;
  int* oimg = out + img * NP;
  for (int j = t; j < NP; j += 1024) {
    int lab = c[rimg[j]] - 1;
    oimg[j] = (lab < MAXSEG - 1) ? lab : (MAXSEG - 1);
  }
}

extern "C" void kernel_launch(void* const* d_in, const int* in_sizes, int n_in,
                              void* d_out, int out_size, void* d_ws, size_t ws_size,
                              hipStream_t stream) {
  const float* x = (const float*)d_in[0];
  int* out = (int*)d_out;
  char* ws = (char*)d_ws;

  // workspace layout (~1.70 MB).
  // part (4 x IMGS*NP floats = 524288 B) aliases bufL — bufL dead after k_blur.
  // pkeys (2 x IMGS*NP u64 = 524288 B) aliases the same region — part dead
  // after k_densmerge; k_par writes pkeys after that (in-stream order).
  float4* pf   = (float4*)(ws);                         // 2*24576*16 = 786432
  float4* bufL = (float4*)(ws + 786432);                // 524288 (lab output)
  float* part  = (float*)(ws + 786432);                 // alias bufL, 524288
  unsigned long long* pkeys = (unsigned long long*)(ws + 786432);  // alias, 524288
  int* parent  = (int*)(ws + 1310720);                  // 131072
  int* root    = (int*)(ws + 1441792);                  // 131072
  int* cums    = (int*)(ws + 1572864);                  // 131072

  const int total = IMGS * NP;                          // 32768
  const int ptotal = IMGS * PIMG;                       // 49152

  k_prep<<<(ptotal + 255) / 256, 256, 0, stream>>>(x, pf, bufL);
  k_blur<<<IMGS * H, 384, 0, stream>>>(bufL, pf);
  k_dens<<<1024, 512, 0, stream>>>(pf, part);
  k_densmerge<<<total / 256, 256, 0, stream>>>(part, pf);
  k_par<<<1024, 512, 0, stream>>>(pf, pkeys);
  k_merge<<<total / 256, 256, 0, stream>>>(pkeys, parent);
  k_root<<<total / 256, 256, 0, stream>>>(parent, root);
  k_scanlabel<<<IMGS, 1024, 0, stream>>>(parent, root, cums, out);
}

// Round 18
// 148.643 us; speedup vs baseline: 1.7183x; 1.0126x over previous
//
#include <hip/hip_runtime.h>
#include <math.h>

static constexpr int IMGS = 2;
static constexpr int H = 128, W = 128;
static constexpr int NP = H * W;           // 16384
static constexpr int KWIN = 30;            // quickshift window radius (ceil(3*10))
static constexpr int PR = 20;              // parent prune radius: dr^2+dc^2>400 can't win (MAX_DIST=20)
static constexpr int GR = 20;              // gaussian radius int(4*5+0.5)
static constexpr float INV = 0.005f;       // 0.5 / (10*10)
static constexpr int MAXSEG = 40;

// padded feature layout: row stride 192 float4, cols [30,158) hold the image.
// float4 = (L, a, b, dens); pads = (1e6,1e6,1e6,-inf).
static constexpr int PSTR = 192;
static constexpr int PIMG = H * PSTR;      // 24576 float4 per image
static constexpr int NSEG = 64 + 2 * PR;   // 104 staged float4 per k_par row
static constexpr int NSEGD = 64 + 2 * KWIN; // 124 staged float4 per k_dens row

typedef float f32x2 __attribute__((ext_vector_type(2)));

// ---------------- prep: pf sentinel fill + rgb2lab into bufL -------------------
__global__ void k_prep(const float* __restrict__ x, float4* __restrict__ pf,
                       float4* __restrict__ bufL) {
#pragma clang fp contract(off)
  int i = blockIdx.x * blockDim.x + threadIdx.x;
  if (i < IMGS * PIMG) pf[i] = make_float4(1e6f, 1e6f, 1e6f, -__builtin_inff());
  if (i >= IMGS * NP) return;
  int img = i / NP, p = i % NP;
  const float* base = x + img * 3 * NP;
  float rgb[3] = { base[p], base[NP + p], base[2 * NP + p] };
  float lin[3];
  for (int c = 0; c < 3; ++c) {
    float v = rgb[c];
    lin[c] = (v > 0.04045f) ? powf((v + 0.055f) / 1.055f, 2.4f) : (v / 12.92f);
  }
  const float M[3][3] = {{0.412453f, 0.357580f, 0.180423f},
                         {0.212671f, 0.715160f, 0.072169f},
                         {0.019334f, 0.119193f, 0.950227f}};
  const float wp[3] = {0.95047f, 1.0f, 1.08883f};
  float f[3];
  for (int j = 0; j < 3; ++j) {
    float s = lin[0] * M[j][0];
    s = s + lin[1] * M[j][1];
    s = s + lin[2] * M[j][2];
    float xyz = s / wp[j];
    f[j] = (xyz > 0.008856f) ? cbrtf(fmaxf(xyz, 1e-8f))
                             : (7.787f * xyz + (float)(16.0 / 116.0));
  }
  float L = 116.0f * f[1] - 16.0f;
  float a = 500.0f * (f[0] - f[1]);
  float b = 200.0f * (f[1] - f[2]);
  bufL[i] = make_float4(L, a, b, 0.0f);
}

// ---------------- fused separable gaussian (V then H), symmetric pad -----------
__global__ __launch_bounds__(384)
void k_blur(const float4* __restrict__ bufL, float4* __restrict__ pf) {
#pragma clang fp contract(off)
  __shared__ float w[2 * GR + 1];
  __shared__ float mid[3][128];
  if (threadIdx.x == 0) {
    double k[2 * GR + 1];
    double s = 0.0;
    for (int i = -GR; i <= GR; ++i) {
      double t = (double)i / 5.0;
      double v = exp(-0.5 * t * t);
      k[i + GR] = v;
      s += v;
    }
    for (int i = 0; i < 2 * GR + 1; ++i) w[i] = (float)(k[i] / s);
  }
  __syncthreads();
  int tid = threadIdx.x;
  int c = tid >> 7;                         // 0..2
  int xx = tid & 127;
  int b = blockIdx.x;                       // img*128 + y
  int y = b & 127, img = b >> 7;
  const float* base = (const float*)(bufL + img * NP);
  float a = 0.0f;
  for (int t = 0; t <= 2 * GR; ++t) {
    int yy = y - GR + t;
    if (yy < 0) yy = -yy - 1;
    if (yy >= H) yy = 2 * H - 1 - yy;
    a = a + w[t] * base[(yy * W + xx) * 4 + c];
  }
  mid[c][xx] = a;
  __syncthreads();
  float o = 0.0f;
  for (int t = 0; t <= 2 * GR; ++t) {
    int xq = xx - GR + t;
    if (xq < 0) xq = -xq - 1;
    if (xq >= W) xq = 2 * W - 1 - xq;
    o = o + w[t] * mid[c][xq];
  }
  ((float*)(pf + img * PIMG + y * PSTR + xx + KWIN))[c] = o;  // 4B store, no race
}

// ---------------- density: LDS pair-staged, dc-stripe waves --------------------
// (R17 structure. R18: blockIdx->work decode SWIZZLED for load balance — the
// union window is 32..62 rows depending on ygrp, and consecutive blockIdx
// (which co-reside on a CU) used to share one ygrp, so interior CUs ran 62-row
// blocks while edge CUs idled at ~60% (VALUBusy 58%). New decode spreads each
// consecutive 4-block group across ygrps 16 apart: pure bijective index remap,
// identical (img,ygrp,tile,q) work and part slots => zero numeric change.)
template<int DB, int DE>
__device__ inline void dens_stripe2(const float4* __restrict__ rb,
                                    float4 fc0, float4 fc1,
                                    float s0, float s1, int lane,
                                    float& acc0, float& acc1) {
#pragma clang fp contract(off)
  const f32x2 nInv = { -INV, -INV };
#pragma unroll
  for (int d0 = DB; d0 + 1 < DE; d0 += 2) {
    float4 nb0 = rb[lane + d0];
    float4 nb1 = rb[lane + d0 + 1];
    float c0 = (float)((d0 - KWIN) * (d0 - KWIN));
    float c1 = (float)((d0 + 1 - KWIN) * (d0 + 1 - KWIN));
    // center 0
    f32x2 dx0 = { fc0.x - nb0.x, fc0.x - nb1.x };
    f32x2 dy0 = { fc0.y - nb0.y, fc0.y - nb1.y };
    f32x2 dz0 = { fc0.z - nb0.z, fc0.z - nb1.z };
    f32x2 dd0 = (dx0 * dx0 + dy0 * dy0) + dz0 * dz0;
    f32x2 sp0 = { s0 + c0, s0 + c1 };     // exact: ints < 2^11 (or inf)
    dd0 = dd0 + sp0;
    f32x2 e0 = dd0 * nInv;                // bit == -(d*INV)
    acc0 = acc0 + __expf(e0.x);           // in-order within stripe
    acc0 = acc0 + __expf(e0.y);
    // center 1 (same staged neighbors)
    f32x2 dx1 = { fc1.x - nb0.x, fc1.x - nb1.x };
    f32x2 dy1 = { fc1.y - nb0.y, fc1.y - nb1.y };
    f32x2 dz1 = { fc1.z - nb0.z, fc1.z - nb1.z };
    f32x2 dd1 = (dx1 * dx1 + dy1 * dy1) + dz1 * dz1;
    f32x2 sp1 = { s1 + c0, s1 + c1 };
    dd1 = dd1 + sp1;
    f32x2 e1 = dd1 * nInv;
    acc1 = acc1 + __expf(e1.x);
    acc1 = acc1 + __expf(e1.y);
  }
  if constexpr ((DE - DB) & 1) {          // scalar tail
    constexpr int dcu = DE - 1;
    float4 nb = rb[lane + dcu];
    float ct = (float)((dcu - KWIN) * (dcu - KWIN));
    float a0 = fc0.x - nb.x, a1 = fc0.y - nb.y, a2 = fc0.z - nb.z;
    float d0 = (a0 * a0 + a1 * a1) + a2 * a2;
    d0 = d0 + (s0 + ct);
    acc0 = acc0 + __expf(-d0 * INV);
    float b0 = fc1.x - nb.x, b1 = fc1.y - nb.y, b2 = fc1.z - nb.z;
    float d1 = (b0 * b0 + b1 * b1) + b2 * b2;
    d1 = d1 + (s1 + ct);
    acc1 = acc1 + __expf(-d1 * INV);
  }
}

template<int DB, int DE>
__device__ inline void dens_two_rows(const float4* __restrict__ bufA,
                                     const float4* __restrict__ bufB,
                                     float4 fc0, float4 fc1, int lane,
                                     int y0, int y1, int nyA, bool haveB,
                                     float& acc0, float& acc1) {
#pragma clang fp contract(off)
  {
    int dr0 = nyA - y0, dr1 = nyA - y1;
    float s0 = (nyA <= y0 + KWIN) ? (float)(dr0 * dr0) : __builtin_inff();
    float s1 = (nyA >= y1 - KWIN) ? (float)(dr1 * dr1) : __builtin_inff();
    dens_stripe2<DB, DE>(bufA, fc0, fc1, s0, s1, lane, acc0, acc1);
  }
  if (haveB) {
    int nyB = nyA + 1;
    int dr0 = nyB - y0, dr1 = nyB - y1;
    float s0 = (nyB <= y0 + KWIN) ? (float)(dr0 * dr0) : __builtin_inff();
    float s1 = (nyB >= y1 - KWIN) ? (float)(dr1 * dr1) : __builtin_inff();
    dens_stripe2<DB, DE>(bufB, fc0, fc1, s0, s1, lane, acc0, acc1);
  }
}

__global__ __launch_bounds__(512, 4)
void k_dens(const float4* __restrict__ pf, float* __restrict__ part) {
#pragma clang fp contract(off)
  __shared__ float4 aos[2][2][NSEGD];      // [buf][row-of-pair][col]
  __shared__ float pbuf[8][2][64];
  int tid = threadIdx.x;
  int lane = tid & 63;
  int wave = tid >> 6;
  int b = blockIdx.x;                      // 1024 blocks, swizzled decode:
  // ygrp from b[1:0]<<4 | b[5:2] -> consecutive blocks span ygrps 16 apart
  int ygrp = ((b & 3) << 4) | ((b >> 2) & 15);
  int tile = (b >> 6) & 1, q = (b >> 7) & 3, img = (b >> 9) & 1;
  int y0 = ygrp * 2, y1 = y0 + 1;
  int x0 = tile * 64;
  const float4* fimg = pf + img * PIMG;
  float4 fc0 = fimg[y0 * PSTR + x0 + lane + KWIN];
  float4 fc1 = fimg[y1 * PSTR + x0 + lane + KWIN];
  int lo = y0 - KWIN; if (lo < 0) lo = 0;
  int hi = y1 + KWIN; if (hi > H - 1) hi = H - 1;
  int nr = hi - lo + 1;                    // 32..62 union rows
  int base = nr >> 2, rem = nr & 3;        // quarter row chunks (base >= 8)
  int cnt = base + (q < rem ? 1 : 0);
  int start = lo + q * base + (q < rem ? q : rem);
  int end = start + cnt;
  // pair staging: 2 rows x NSEGD float4 = 2*248 float2; threads 0..247 stage
  // row A, threads 256..503 stage row B (mirrors k_par's proven pattern).
  int rsel = tid >> 8;                     // 0..1
  int sidx = tid & 255;                    // float2 index within row
  {
    int rA = start;
    int rB = (start + 1 < end) ? start + 1 : start;  // clamp (unused if !B)
    int rr = rsel ? rB : rA;
    if (sidx < NSEGD * 2) {
      float2 v = *(const float2*)(((const float*)(fimg + rr * PSTR + x0)) + sidx * 2);
      *(float2*)(((float*)&aos[0][rsel][0]) + sidx * 2) = v;
    }
  }
  __syncthreads();
  float acc0 = 0.0f, acc1 = 0.0f;
  int npairs = (cnt + 1) >> 1;
  for (int p = 0; p < npairs; ++p) {
    int kb = p & 1;
    float2 pv;
    bool pre = (p + 1 < npairs);
    if (pre) {                             // issue next-pair global loads early
      int nA = start + 2 * (p + 1);
      int nB = (nA + 1 < end) ? nA + 1 : nA;
      int pr_row = rsel ? nB : nA;
      if (sidx < NSEGD * 2)
        pv = *(const float2*)(((const float*)(fimg + pr_row * PSTR + x0)) + sidx * 2);
    }
    int nyA = start + 2 * p;
    bool haveB = (nyA + 1 < end);          // wave-uniform
    const float4* bufA = &aos[kb][0][0];
    const float4* bufB = &aos[kb][1][0];
    if      (wave == 0) dens_two_rows< 0,  8>(bufA, bufB, fc0, fc1, lane, y0, y1, nyA, haveB, acc0, acc1);
    else if (wave == 1) dens_two_rows< 8, 16>(bufA, bufB, fc0, fc1, lane, y0, y1, nyA, haveB, acc0, acc1);
    else if (wave == 2) dens_two_rows<16, 24>(bufA, bufB, fc0, fc1, lane, y0, y1, nyA, haveB, acc0, acc1);
    else if (wave == 3) dens_two_rows<24, 32>(bufA, bufB, fc0, fc1, lane, y0, y1, nyA, haveB, acc0, acc1);
    else if (wave == 4) dens_two_rows<32, 40>(bufA, bufB, fc0, fc1, lane, y0, y1, nyA, haveB, acc0, acc1);
    else if (wave == 5) dens_two_rows<40, 48>(bufA, bufB, fc0, fc1, lane, y0, y1, nyA, haveB, acc0, acc1);
    else if (wave == 6) dens_two_rows<48, 56>(bufA, bufB, fc0, fc1, lane, y0, y1, nyA, haveB, acc0, acc1);
    else                dens_two_rows<56, 61>(bufA, bufB, fc0, fc1, lane, y0, y1, nyA, haveB, acc0, acc1);
    if (pre && sidx < NSEGD * 2)           // write other buffer: no race now
      *(float2*)(((float*)&aos[kb ^ 1][rsel][0]) + sidx * 2) = pv;
    __syncthreads();                       // publish next pair
  }
  pbuf[wave][0][lane] = acc0;              // publish dc-stripe partials
  pbuf[wave][1][lane] = acc1;
  __syncthreads();
  if (wave < 2) {                          // wave w folds center row y0+w
    float a = pbuf[0][wave][lane];
#pragma unroll
    for (int w = 1; w < 8; ++w) a = a + pbuf[w][wave][lane];
    part[q * (IMGS * NP) + img * NP + (y0 + wave) * W + x0 + lane] = a;
  }
}

// ---------------- fold the 4 row-quarter partials into pf.w --------------------
// Ascending-q = ascending-row order, left-to-right: bitwise-deterministic.
__global__ void k_densmerge(const float* __restrict__ part, float4* __restrict__ pf) {
#pragma clang fp contract(off)
  int i = blockIdx.x * blockDim.x + threadIdx.x;
  if (i >= IMGS * NP) return;
  int img = i / NP, p = i % NP, y = p >> 7, x = p & 127;
  float s = ((part[i] + part[IMGS * NP + i]) + part[2 * IMGS * NP + i])
            + part[3 * IMGS * NP + i];
  pf[img * PIMG + y * PSTR + x + KWIN].w = s;
}

// ---------------- parent: +-20 pruned window, half-split, AoS b128, pairs ------
// (R11, validated. R18: same load-balance swizzle — y from spread bits.)
template<int DB, int DE>
__device__ inline void par_pairs(const float4* __restrict__ rb,
                                 int lane, f32x2 fcx, f32x2 fcy, f32x2 fcz,
                                 float dcen, float sprf, int qbase,
                                 float& bestd, int& bestp) {
#pragma clang fp contract(off)
#pragma unroll
  for (int d0 = DB; d0 + 1 < DE; d0 += 2) {
    int i0 = lane + d0;
    float4 nb0 = rb[i0];
    float4 nb1 = rb[i0 + 1];
    f32x2 nx = { nb0.x, nb1.x };
    f32x2 nv = { nb0.y, nb1.y };
    f32x2 nz = { nb0.z, nb1.z };
    f32x2 nw = { nb0.w, nb1.w };
    f32x2 dx = fcx - nx, dy = fcy - nv, dz = fcz - nz;
    f32x2 dd = (dx * dx + dy * dy) + dz * dz;
    f32x2 sp = { sprf + (float)((d0 - PR) * (d0 - PR)),
                 sprf + (float)((d0 + 1 - PR) * (d0 + 1 - PR)) };
    dd = dd + sp;                          // exact (ints < 2^11)
    int b0 = (nw.x > dcen) & (dd.x < bestd);
    bestd = b0 ? dd.x : bestd;
    bestp = b0 ? (qbase + d0 - PR) : bestp;
    int b1 = (nw.y > dcen) & (dd.y < bestd);
    bestd = b1 ? dd.y : bestd;
    bestp = b1 ? (qbase + d0 + 1 - PR) : bestp;
  }
  if constexpr ((DE - DB) & 1) {           // scalar tail
    constexpr int dcu = DE - 1;
    float4 nb = rb[lane + dcu];
    float nd = nb.w;
    float d0 = fcx.x - nb.x, d1 = fcy.x - nb.y, d2 = fcz.x - nb.z;
    float d = (d0 * d0 + d1 * d1) + d2 * d2;
    d = d + (sprf + (float)((dcu - PR) * (dcu - PR)));
    int bt = (nd > dcen) & (d < bestd);
    bestd = bt ? d : bestd;
    bestp = bt ? (qbase + dcu - PR) : bestp;
  }
}

template<int DB, int DE>
__device__ inline void par_two_rows(const float4* __restrict__ bufA,
                                    const float4* __restrict__ bufB,
                                    int lane, f32x2 fcx, f32x2 fcy, f32x2 fcz,
                                    float dcen, int y, int x,
                                    int nyA, bool haveB,
                                    float& bestd, int& bestp) {
#pragma clang fp contract(off)
  int drA = nyA - y;
  par_pairs<DB, DE>(bufA, lane, fcx, fcy, fcz, dcen,
                    (float)(drA * drA), nyA * W + x, bestd, bestp);
  if (haveB) {
    int drB = nyA + 1 - y;
    par_pairs<DB, DE>(bufB, lane, fcx, fcy, fcz, dcen,
                      (float)(drB * drB), (nyA + 1) * W + x, bestd, bestp);
  }
}

__global__ __launch_bounds__(512, 4)
void k_par(const float4* __restrict__ pf, unsigned long long* __restrict__ pkeys) {
#pragma clang fp contract(off)
  __shared__ float4 aos[2][2][NSEG];       // [buf][row-of-pair][col]
  __shared__ unsigned long long m_k[8][64];
  int tid = threadIdx.x, lane = tid & 63, wave = tid >> 6;
  int b = blockIdx.x;                      // 1024 blocks, swizzled decode:
  // y from b[2:0]<<4 | b[6:3] -> consecutive blocks span y 16 apart
  int y = ((b & 7) << 4) | ((b >> 3) & 15);
  int half = (b >> 7) & 1, tile = (b >> 8) & 1, img = (b >> 9) & 1;
  int x0 = tile * 64, x = x0 + lane;
  const float4* fimg = pf + img * PIMG;
  float4 fc = fimg[y * PSTR + x + KWIN];
  float dcen = fc.w;
  f32x2 fcx = { fc.x, fc.x }, fcy = { fc.y, fc.y }, fcz = { fc.z, fc.z };
  int ny0 = y - PR; if (ny0 < 0) ny0 = 0;
  int ny1 = y + PR; if (ny1 > H - 1) ny1 = H - 1;
  int nr = ny1 - ny0 + 1;                  // 21..41
  int h0 = nr >> 1;                        // rows in half 0
  int hb = half ? (ny0 + h0) : ny0;
  int he = half ? (ny1 + 1) : (ny0 + h0);
  int cnt = he - hb;                       // >= 10
  // pair staging: 2 rows x NSEG float4 = 2*208 float2; threads 0..207 stage
  // row A (float2 index sidx), threads 256..463 stage row B.
  int rsel = tid >> 8;                     // 0..1
  int sidx = tid & 255;                    // float2 index within row
  const int segoff = x0 + (KWIN - PR);     // staged cols = x0-PR .. x0+63+PR
  {
    int rA = hb;
    int rB = (hb + 1 < he) ? hb + 1 : hb;  // clamp (unused if no row B)
    int rr = rsel ? rB : rA;
    if (sidx < NSEG * 2) {
      float2 v = *(const float2*)(((const float*)(fimg + rr * PSTR + segoff)) + sidx * 2);
      *(float2*)(((float*)&aos[0][rsel][0]) + sidx * 2) = v;
    }
  }
  __syncthreads();
  float bestd = __builtin_inff();
  int bestp = y * W + x;
  int npairs = (cnt + 1) >> 1;
  for (int p = 0; p < npairs; ++p) {
    int kb = p & 1;
    float2 pv;
    bool pre = (p + 1 < npairs);
    if (pre) {                             // issue next-pair global loads early
      int nA = hb + 2 * (p + 1);
      int nB = (nA + 1 < he) ? nA + 1 : nA;
      int pr_row = rsel ? nB : nA;
      if (sidx < NSEG * 2)
        pv = *(const float2*)(((const float*)(fimg + pr_row * PSTR + segoff)) + sidx * 2);
    }
    int nyA = hb + 2 * p;
    bool haveB = (nyA + 1 < he);           // wave-uniform
    const float4* bufA = &aos[kb][0][0];
    const float4* bufB = &aos[kb][1][0];
    if      (wave == 0) par_two_rows< 0,  6>(bufA, bufB, lane, fcx, fcy, fcz, dcen, y, x, nyA, haveB, bestd, bestp);
    else if (wave == 1) par_two_rows< 6, 11>(bufA, bufB, lane, fcx, fcy, fcz, dcen, y, x, nyA, haveB, bestd, bestp);
    else if (wave == 2) par_two_rows<11, 16>(bufA, bufB, lane, fcx, fcy, fcz, dcen, y, x, nyA, haveB, bestd, bestp);
    else if (wave == 3) par_two_rows<16, 21>(bufA, bufB, lane, fcx, fcy, fcz, dcen, y, x, nyA, haveB, bestd, bestp);
    else if (wave == 4) par_two_rows<21, 26>(bufA, bufB, lane, fcx, fcy, fcz, dcen, y, x, nyA, haveB, bestd, bestp);
    else if (wave == 5) par_two_rows<26, 31>(bufA, bufB, lane, fcx, fcy, fcz, dcen, y, x, nyA, haveB, bestd, bestp);
    else if (wave == 6) par_two_rows<31, 36>(bufA, bufB, lane, fcx, fcy, fcz, dcen, y, x, nyA, haveB, bestd, bestp);
    else                par_two_rows<36, 41>(bufA, bufB, lane, fcx, fcy, fcz, dcen, y, x, nyA, haveB, bestd, bestp);
    if (pre && sidx < NSEG * 2)            // write other buffer: no race now
      *(float2*)(((float*)&aos[kb ^ 1][rsel][0]) + sidx * 2) = pv;
    __syncthreads();                       // publish next pair
  }
  // pack (d, q): inf (no candidate) sorts above all finite d
  m_k[wave][lane] =
      ((unsigned long long)__float_as_uint(bestd) << 32) | (unsigned)bestp;
  __syncthreads();
  if (wave == 0) {
    unsigned long long k = m_k[0][lane];
#pragma unroll
    for (int w = 1; w < 8; ++w) {
      unsigned long long kw = m_k[w][lane];
      k = (kw < k) ? kw : k;
    }
    pkeys[half * (IMGS * NP) + img * NP + y * W + x] = k;
  }
}

// ---------------- merge halves -> parent ---------------------------------------
__global__ void k_merge(const unsigned long long* __restrict__ pkeys,
                        int* __restrict__ parent) {
  int i = blockIdx.x * blockDim.x + threadIdx.x;
  if (i >= IMGS * NP) return;
  unsigned long long k0 = pkeys[i], k1 = pkeys[IMGS * NP + i];
  unsigned long long k = (k0 < k1) ? k0 : k1;
  float bd = __uint_as_float((unsigned)(k >> 32));
  int p = i % NP;
  parent[i] = (bd > 400.0f) ? p : (int)(k & 0xffffffffu);  // sqrt(d) > max_dist
}

// ---------------- root find via path-halving union-find (R31, validated) -------
// Races are BENIGN: every write replaces a parent with a strict ancestor
// (forest acyclic: density strictly increases along chains), so concurrent
// threads cooperatively compress shared paths — ~O(log) steps each. root[] is
// the chain's unique fixed point => bit-identical to a serial chase. Root
// flags (parent[i]==i) preserved: roots never rewritten; a non-root's new
// parent is an ancestor != itself.
__global__ void k_root(int* __restrict__ parent, int* __restrict__ root) {
  int i = blockIdx.x * blockDim.x + threadIdx.x;
  if (i >= IMGS * NP) return;
  int img = i / NP, p = i % NP;
  int* par = parent + img * NP;
  int v = p;
  int pr = par[v];
  int gp = par[pr];
  while (pr != gp) {
    par[v] = gp;                           // halve (benign race: gp = ancestor)
    v = gp;
    pr = par[v];
    gp = par[pr];
  }
  root[i] = pr;
}

// ---------------- scan of root flags + final labels (fused, coalesced) ---------
__global__ __launch_bounds__(1024)
void k_scanlabel(const int* __restrict__ parent, const int* __restrict__ root,
                 int* __restrict__ cums, int* __restrict__ out) {
  __shared__ int part[1024];
  int img = blockIdx.x;
  int t = threadIdx.x;                     // 1024 threads x 16 elements
  const int* par = parent + img * NP;
  int base = t * 16;
  int f[16];
  const int4* p4 = (const int4*)(par + base);
#pragma unroll
  for (int j = 0; j < 4; ++j) {
    int4 v = p4[j];
    f[4 * j + 0] = (v.x == base + 4 * j + 0);
    f[4 * j + 1] = (v.y == base + 4 * j + 1);
    f[4 * j + 2] = (v.z == base + 4 * j + 2);
    f[4 * j + 3] = (v.w == base + 4 * j + 3);
  }
  int s = 0;
#pragma unroll
  for (int j = 0; j < 16; ++j) s += f[j];
  part[t] = s;
  __syncthreads();
  for (int off = 1; off < 1024; off <<= 1) {
    int add = (t >= off) ? part[t - off] : 0;
    __syncthreads();
    part[t] += add;
    __syncthreads();
  }
  int run = part[t] - s;                   // exclusive prefix of this chunk
  int* c = cums + img * NP;
#pragma unroll
  for (int j = 0; j < 16; ++j) { run += f[j]; c[base + j] = run; }
  __threadfence_block();
  __syncthreads();                         // block-visible global writes
  const int* rimg = root + img * NP;
  int* oimg = out + img * NP;
  for (int j = t; j < NP; j += 1024) {
    int lab = c[rimg[j]] - 1;
    oimg[j] = (lab < MAXSEG - 1) ? lab : (MAXSEG - 1);
  }
}

extern "C" void kernel_launch(void* const* d_in, const int* in_sizes, int n_in,
                              void* d_out, int out_size, void* d_ws, size_t ws_size,
                              hipStream_t stream) {
  const float* x = (const float*)d_in[0];
  int* out = (int*)d_out;
  char* ws = (char*)d_ws;

  // workspace layout (~1.70 MB).
  // part (4 x IMGS*NP floats = 524288 B) aliases bufL — bufL dead after k_blur.
  // pkeys (2 x IMGS*NP u64 = 524288 B) aliases the same region — part dead
  // after k_densmerge; k_par writes pkeys after that (in-stream order).
  float4* pf   = (float4*)(ws);                         // 2*24576*16 = 786432
  float4* bufL = (float4*)(ws + 786432);                // 524288 (lab output)
  float* part  = (float*)(ws + 786432);                 // alias bufL, 524288
  unsigned long long* pkeys = (unsigned long long*)(ws + 786432);  // alias, 524288
  int* parent  = (int*)(ws + 1310720);                  // 131072
  int* root    = (int*)(ws + 1441792);                  // 131072
  int* cums    = (int*)(ws + 1572864);                  // 131072

  const int total = IMGS * NP;                          // 32768
  const int ptotal = IMGS * PIMG;                       // 49152

  k_prep<<<(ptotal + 255) / 256, 256, 0, stream>>>(x, pf, bufL);
  k_blur<<<IMGS * H, 384, 0, stream>>>(bufL, pf);
  k_dens<<<1024, 512, 0, stream>>>(pf, part);
  k_densmerge<<<total / 256, 256, 0, stream>>>(part, pf);
  k_par<<<1024, 512, 0, stream>>>(pf, pkeys);
  k_merge<<<total / 256, 256, 0, stream>>>(pkeys, parent);
  k_root<<<total / 256, 256, 0, stream>>>(parent, root);
  k_scanlabel<<<IMGS, 1024, 0, stream>>>(parent, root, cums, out);
}

// Round 20
// 141.290 us; speedup vs baseline: 1.8077x; 1.0520x over previous
//
#include <hip/hip_runtime.h>
#include <math.h>

static constexpr int IMGS = 2;
static constexpr int H = 128, W = 128;
static constexpr int NP = H * W;           // 16384
static constexpr int KWIN = 30;            // quickshift window radius (ceil(3*10))
static constexpr int PR = 20;              // parent prune radius: dr^2+dc^2>400 can't win (MAX_DIST=20)
static constexpr int GR = 20;              // gaussian radius int(4*5+0.5)
static constexpr float INV = 0.005f;       // 0.5 / (10*10)
static constexpr int MAXSEG = 40;

// padded feature layout: row stride 192 float4, cols [30,158) hold the image.
// float4 = (L, a, b, dens); pads = (1e6,1e6,1e6,-inf).
static constexpr int PSTR = 192;
static constexpr int PIMG = H * PSTR;      // 24576 float4 per image
static constexpr int NSEG = 64 + 2 * PR;   // 104 staged float4 per k_par row
static constexpr int NSEGD = 64 + 2 * KWIN; // 124 staged float4 per k_dens row

typedef float f32x2 __attribute__((ext_vector_type(2)));

// ---------------- prep: pf sentinel fill + rgb2lab into bufL -------------------
__global__ void k_prep(const float* __restrict__ x, float4* __restrict__ pf,
                       float4* __restrict__ bufL) {
#pragma clang fp contract(off)
  int i = blockIdx.x * blockDim.x + threadIdx.x;
  if (i < IMGS * PIMG) pf[i] = make_float4(1e6f, 1e6f, 1e6f, -__builtin_inff());
  if (i >= IMGS * NP) return;
  int img = i / NP, p = i % NP;
  const float* base = x + img * 3 * NP;
  float rgb[3] = { base[p], base[NP + p], base[2 * NP + p] };
  float lin[3];
  for (int c = 0; c < 3; ++c) {
    float v = rgb[c];
    lin[c] = (v > 0.04045f) ? powf((v + 0.055f) / 1.055f, 2.4f) : (v / 12.92f);
  }
  const float M[3][3] = {{0.412453f, 0.357580f, 0.180423f},
                         {0.212671f, 0.715160f, 0.072169f},
                         {0.019334f, 0.119193f, 0.950227f}};
  const float wp[3] = {0.95047f, 1.0f, 1.08883f};
  float f[3];
  for (int j = 0; j < 3; ++j) {
    float s = lin[0] * M[j][0];
    s = s + lin[1] * M[j][1];
    s = s + lin[2] * M[j][2];
    float xyz = s / wp[j];
    f[j] = (xyz > 0.008856f) ? cbrtf(fmaxf(xyz, 1e-8f))
                             : (7.787f * xyz + (float)(16.0 / 116.0));
  }
  float L = 116.0f * f[1] - 16.0f;
  float a = 500.0f * (f[0] - f[1]);
  float b = 200.0f * (f[1] - f[2]);
  bufL[i] = make_float4(L, a, b, 0.0f);
}

// ---------------- fused separable gaussian (V then H), symmetric pad -----------
__global__ __launch_bounds__(384)
void k_blur(const float4* __restrict__ bufL, float4* __restrict__ pf) {
#pragma clang fp contract(off)
  __shared__ float w[2 * GR + 1];
  __shared__ float mid[3][128];
  if (threadIdx.x == 0) {
    double k[2 * GR + 1];
    double s = 0.0;
    for (int i = -GR; i <= GR; ++i) {
      double t = (double)i / 5.0;
      double v = exp(-0.5 * t * t);
      k[i + GR] = v;
      s += v;
    }
    for (int i = 0; i < 2 * GR + 1; ++i) w[i] = (float)(k[i] / s);
  }
  __syncthreads();
  int tid = threadIdx.x;
  int c = tid >> 7;                         // 0..2
  int xx = tid & 127;
  int b = blockIdx.x;                       // img*128 + y
  int y = b & 127, img = b >> 7;
  const float* base = (const float*)(bufL + img * NP);
  float a = 0.0f;
  for (int t = 0; t <= 2 * GR; ++t) {
    int yy = y - GR + t;
    if (yy < 0) yy = -yy - 1;
    if (yy >= H) yy = 2 * H - 1 - yy;
    a = a + w[t] * base[(yy * W + xx) * 4 + c];
  }
  mid[c][xx] = a;
  __syncthreads();
  float o = 0.0f;
  for (int t = 0; t <= 2 * GR; ++t) {
    int xq = xx - GR + t;
    if (xq < 0) xq = -xq - 1;
    if (xq >= W) xq = 2 * W - 1 - xq;
    o = o + w[t] * mid[c][xq];
  }
  ((float*)(pf + img * PIMG + y * PSTR + xx + KWIN))[c] = o;  // 4B store, no race
}

// ---------------- density: dot-form, LDS pair-staged, dc-stripe waves ----------
// R19: k_dens was pinned at its VALU-issue floor (issue-cycle model == 50us
// measured across 5 rounds). Restructure the per-term math via
// |fc-nb|^2 = |fc|^2 - 2 fc.nb + |nb|^2, pre-scaled by -INV:
//   e = bI + (hnI + cdcI) + (2INV*fc) . nb,   term = __expf(e)
// where hnI = -INV*|nb|^2 is computed ONCE per staged neighbor (stored in the
// dead .w slot — pf.w is still the -inf sentinel when k_dens runs), bI =
// -INV*(|fc|^2 + sprf) once per (center,row), cdcI = -INV*(dc-30)^2 folds at
// compile time. Inner loop (fp contract fast, pk_fma): 11 pk + 4 exp per
// 2-terms x 2-centers vs ~22 before — exp becomes the dominant cost.
// Numerics: per-term rounding-path change ~1e-7 rel on dens — an order BELOW
// the accepted __expf deviation (~1e-6). Pads: hnI = -1.5e10 => exp -> +0.0
// exactly; inactive rows: bI = -inf => exp -> +0.0, no NaN (other addends
// finite). Even/odd-dc pk accumulator + .x+.y fold = same deterministic
// positive-sum reassociation class passed since R2. k_par untouched (exact).
template<int DB, int DE>
__device__ inline void dens_stripe2(const float4* __restrict__ rb,
                                    f32x2 fx0, f32x2 fy0, f32x2 fz0,
                                    f32x2 fx1, f32x2 fy1, f32x2 fz1,
                                    float bI0, float bI1, int lane,
                                    f32x2& av0, f32x2& av1) {
#pragma clang fp contract(fast)
#pragma unroll
  for (int d0 = DB; d0 + 1 < DE; d0 += 2) {
    float4 nb0 = rb[lane + d0];
    float4 nb1 = rb[lane + d0 + 1];
    f32x2 nx = { nb0.x, nb1.x };
    f32x2 ny = { nb0.y, nb1.y };
    f32x2 nz = { nb0.z, nb1.z };
    const f32x2 cdcI = { -INV * (float)((d0 - KWIN) * (d0 - KWIN)),
                         -INV * (float)((d0 + 1 - KWIN) * (d0 + 1 - KWIN)) };
    f32x2 hw = { nb0.w, nb1.w };
    f32x2 hnc = hw + cdcI;                 // shared by both centers
    // center 0
    f32x2 t0 = hnc + (f32x2){ bI0, bI0 };
    t0 = nx * fx0 + t0;                    // pk_fma chain
    t0 = ny * fy0 + t0;
    t0 = nz * fz0 + t0;
    av0 = av0 + (f32x2){ __expf(t0.x), __expf(t0.y) };
    // center 1
    f32x2 t1 = hnc + (f32x2){ bI1, bI1 };
    t1 = nx * fx1 + t1;
    t1 = ny * fy1 + t1;
    t1 = nz * fz1 + t1;
    av1 = av1 + (f32x2){ __expf(t1.x), __expf(t1.y) };
  }
  if constexpr ((DE - DB) & 1) {           // scalar tail (dc = DE-1)
    constexpr int dcu = DE - 1;
    float4 nb = rb[lane + dcu];
    const float cI = -INV * (float)((dcu - KWIN) * (dcu - KWIN));
    float hnc = nb.w + cI;
    float t0 = hnc + bI0;
    t0 = nb.x * fx0.x + t0;
    t0 = nb.y * fy0.x + t0;
    t0 = nb.z * fz0.x + t0;
    av0.x = av0.x + __expf(t0);
    float t1 = hnc + bI1;
    t1 = nb.x * fx1.x + t1;
    t1 = nb.y * fy1.x + t1;
    t1 = nb.z * fz1.x + t1;
    av1.x = av1.x + __expf(t1);
  }
}

template<int DB, int DE>
__device__ inline void dens_two_rows(const float4* __restrict__ bufA,
                                     const float4* __restrict__ bufB,
                                     f32x2 fx0, f32x2 fy0, f32x2 fz0,
                                     f32x2 fx1, f32x2 fy1, f32x2 fz1,
                                     float h0I0, float h0I1, int lane,
                                     int y0, int y1, int nyA, bool haveB,
                                     f32x2& av0, f32x2& av1) {
#pragma clang fp contract(fast)
  {
    int dr0 = nyA - y0, dr1 = nyA - y1;
    float s0 = (nyA <= y0 + KWIN) ? (float)(dr0 * dr0) : __builtin_inff();
    float s1 = (nyA >= y1 - KWIN) ? (float)(dr1 * dr1) : __builtin_inff();
    float bI0 = h0I0 - INV * s0;           // -inf when inactive
    float bI1 = h0I1 - INV * s1;
    dens_stripe2<DB, DE>(bufA, fx0, fy0, fz0, fx1, fy1, fz1, bI0, bI1,
                         lane, av0, av1);
  }
  if (haveB) {
    int nyB = nyA + 1;
    int dr0 = nyB - y0, dr1 = nyB - y1;
    float s0 = (nyB <= y0 + KWIN) ? (float)(dr0 * dr0) : __builtin_inff();
    float s1 = (nyB >= y1 - KWIN) ? (float)(dr1 * dr1) : __builtin_inff();
    float bI0 = h0I0 - INV * s0;
    float bI1 = h0I1 - INV * s1;
    dens_stripe2<DB, DE>(bufB, fx0, fy0, fz0, fx1, fy1, fz1, bI0, bI1,
                         lane, av0, av1);
  }
}

__global__ __launch_bounds__(512, 4)
void k_dens(const float4* __restrict__ pf, float* __restrict__ part) {
#pragma clang fp contract(off)
  __shared__ float4 aos[2][2][NSEGD];      // [buf][row-of-pair][col], .w = hnI
  __shared__ float pbuf[8][2][64];
  int tid = threadIdx.x;
  int lane = tid & 63;
  int wave = tid >> 6;
  int b = blockIdx.x;                      // 1024 blocks, swizzled decode (R18)
  int ygrp = ((b & 3) << 4) | ((b >> 2) & 15);
  int tile = (b >> 6) & 1, q = (b >> 7) & 3, img = (b >> 9) & 1;
  int y0 = ygrp * 2, y1 = y0 + 1;
  int x0 = tile * 64;
  const float4* fimg = pf + img * PIMG;
  float4 fc0 = fimg[y0 * PSTR + x0 + lane + KWIN];
  float4 fc1 = fimg[y1 * PSTR + x0 + lane + KWIN];
  const float TWI = 2.0f * INV;            // 0.01f
  f32x2 fx0 = { fc0.x * TWI, fc0.x * TWI };
  f32x2 fy0 = { fc0.y * TWI, fc0.y * TWI };
  f32x2 fz0 = { fc0.z * TWI, fc0.z * TWI };
  f32x2 fx1 = { fc1.x * TWI, fc1.x * TWI };
  f32x2 fy1 = { fc1.y * TWI, fc1.y * TWI };
  f32x2 fz1 = { fc1.z * TWI, fc1.z * TWI };
  float h0I0 = -INV * (fc0.x * fc0.x + fc0.y * fc0.y + fc0.z * fc0.z);
  float h0I1 = -INV * (fc1.x * fc1.x + fc1.y * fc1.y + fc1.z * fc1.z);
  int lo = y0 - KWIN; if (lo < 0) lo = 0;
  int hi = y1 + KWIN; if (hi > H - 1) hi = H - 1;
  int nr = hi - lo + 1;                    // 32..62 union rows
  int base = nr >> 2, rem = nr & 3;        // quarter row chunks (base >= 8)
  int cnt = base + (q < rem ? 1 : 0);
  int start = lo + q * base + (q < rem ? q : rem);
  int end = start + cnt;
  // pair staging: 2 rows x NSEGD float4; threads 0..123 stage row A float4s,
  // threads 256..379 stage row B; hnI computed once per staged neighbor.
  int rsel = tid >> 8;                     // 0..1
  int fidx = tid & 255;                    // float4 index within row
  {
    int rA = start;
    int rB = (start + 1 < end) ? start + 1 : start;  // clamp (unused if !B)
    int rr = rsel ? rB : rA;
    if (fidx < NSEGD) {
      float4 v = fimg[rr * PSTR + x0 + fidx];
      v.w = -INV * (v.x * v.x + v.y * v.y + v.z * v.z);
      aos[0][rsel][fidx] = v;
    }
  }
  __syncthreads();
  f32x2 av0 = { 0.0f, 0.0f }, av1 = { 0.0f, 0.0f };
  int npairs = (cnt + 1) >> 1;
  for (int p = 0; p < npairs; ++p) {
    int kb = p & 1;
    float4 pv;
    bool pre = (p + 1 < npairs);
    if (pre) {                             // issue next-pair global loads early
      int nA = start + 2 * (p + 1);
      int nB = (nA + 1 < end) ? nA + 1 : nA;
      int pr_row = rsel ? nB : nA;
      if (fidx < NSEGD) {
        pv = fimg[pr_row * PSTR + x0 + fidx];
        pv.w = -INV * (pv.x * pv.x + pv.y * pv.y + pv.z * pv.z);
      }
    }
    int nyA = start + 2 * p;
    bool haveB = (nyA + 1 < end);          // wave-uniform
    const float4* bufA = &aos[kb][0][0];
    const float4* bufB = &aos[kb][1][0];
    if      (wave == 0) dens_two_rows< 0,  8>(bufA, bufB, fx0, fy0, fz0, fx1, fy1, fz1, h0I0, h0I1, lane, y0, y1, nyA, haveB, av0, av1);
    else if (wave == 1) dens_two_rows< 8, 16>(bufA, bufB, fx0, fy0, fz0, fx1, fy1, fz1, h0I0, h0I1, lane, y0, y1, nyA, haveB, av0, av1);
    else if (wave == 2) dens_two_rows<16, 24>(bufA, bufB, fx0, fy0, fz0, fx1, fy1, fz1, h0I0, h0I1, lane, y0, y1, nyA, haveB, av0, av1);
    else if (wave == 3) dens_two_rows<24, 32>(bufA, bufB, fx0, fy0, fz0, fx1, fy1, fz1, h0I0, h0I1, lane, y0, y1, nyA, haveB, av0, av1);
    else if (wave == 4) dens_two_rows<32, 40>(bufA, bufB, fx0, fy0, fz0, fx1, fy1, fz1, h0I0, h0I1, lane, y0, y1, nyA, haveB, av0, av1);
    else if (wave == 5) dens_two_rows<40, 48>(bufA, bufB, fx0, fy0, fz0, fx1, fy1, fz1, h0I0, h0I1, lane, y0, y1, nyA, haveB, av0, av1);
    else if (wave == 6) dens_two_rows<48, 56>(bufA, bufB, fx0, fy0, fz0, fx1, fy1, fz1, h0I0, h0I1, lane, y0, y1, nyA, haveB, av0, av1);
    else                dens_two_rows<56, 61>(bufA, bufB, fx0, fy0, fz0, fx1, fy1, fz1, h0I0, h0I1, lane, y0, y1, nyA, haveB, av0, av1);
    if (pre && fidx < NSEGD)               // write other buffer: no race now
      aos[kb ^ 1][rsel][fidx] = pv;
    __syncthreads();                       // publish next pair
  }
  float acc0 = av0.x + av0.y;              // deterministic even+odd fold
  float acc1 = av1.x + av1.y;
  pbuf[wave][0][lane] = acc0;              // publish dc-stripe partials
  pbuf[wave][1][lane] = acc1;
  __syncthreads();
  if (wave < 2) {                          // wave w folds center row y0+w
    float a = pbuf[0][wave][lane];
#pragma unroll
    for (int w = 1; w < 8; ++w) a = a + pbuf[w][wave][lane];
    part[q * (IMGS * NP) + img * NP + (y0 + wave) * W + x0 + lane] = a;
  }
}

// ---------------- fold the 4 row-quarter partials into pf.w --------------------
// Ascending-q = ascending-row order, left-to-right: bitwise-deterministic.
__global__ void k_densmerge(const float* __restrict__ part, float4* __restrict__ pf) {
#pragma clang fp contract(off)
  int i = blockIdx.x * blockDim.x + threadIdx.x;
  if (i >= IMGS * NP) return;
  int img = i / NP, p = i % NP, y = p >> 7, x = p & 127;
  float s = ((part[i] + part[IMGS * NP + i]) + part[2 * IMGS * NP + i])
            + part[3 * IMGS * NP + i];
  pf[img * PIMG + y * PSTR + x + KWIN].w = s;
}

// ---------------- parent: +-20 pruned window, half-split, AoS b128, pairs ------
// (R11, validated. R18 swizzle. EXACT path — untouched by the R19 dot-form.)
template<int DB, int DE>
__device__ inline void par_pairs(const float4* __restrict__ rb,
                                 int lane, f32x2 fcx, f32x2 fcy, f32x2 fcz,
                                 float dcen, float sprf, int qbase,
                                 float& bestd, int& bestp) {
#pragma clang fp contract(off)
#pragma unroll
  for (int d0 = DB; d0 + 1 < DE; d0 += 2) {
    int i0 = lane + d0;
    float4 nb0 = rb[i0];
    float4 nb1 = rb[i0 + 1];
    f32x2 nx = { nb0.x, nb1.x };
    f32x2 nv = { nb0.y, nb1.y };
    f32x2 nz = { nb0.z, nb1.z };
    f32x2 nw = { nb0.w, nb1.w };
    f32x2 dx = fcx - nx, dy = fcy - nv, dz = fcz - nz;
    f32x2 dd = (dx * dx + dy * dy) + dz * dz;
    f32x2 sp = { sprf + (float)((d0 - PR) * (d0 - PR)),
                 sprf + (float)((d0 + 1 - PR) * (d0 + 1 - PR)) };
    dd = dd + sp;                          // exact (ints < 2^11)
    int b0 = (nw.x > dcen) & (dd.x < bestd);
    bestd = b0 ? dd.x : bestd;
    bestp = b0 ? (qbase + d0 - PR) : bestp;
    int b1 = (nw.y > dcen) & (dd.y < bestd);
    bestd = b1 ? dd.y : bestd;
    bestp = b1 ? (qbase + d0 + 1 - PR) : bestp;
  }
  if constexpr ((DE - DB) & 1) {           // scalar tail
    constexpr int dcu = DE - 1;
    float4 nb = rb[lane + dcu];
    float nd = nb.w;
    float d0 = fcx.x - nb.x, d1 = fcy.x - nb.y, d2 = fcz.x - nb.z;
    float d = (d0 * d0 + d1 * d1) + d2 * d2;
    d = d + (sprf + (float)((dcu - PR) * (dcu - PR)));
    int bt = (nd > dcen) & (d < bestd);
    bestd = bt ? d : bestd;
    bestp = bt ? (qbase + dcu - PR) : bestp;
  }
}

template<int DB, int DE>
__device__ inline void par_two_rows(const float4* __restrict__ bufA,
                                    const float4* __restrict__ bufB,
                                    int lane, f32x2 fcx, f32x2 fcy, f32x2 fcz,
                                    float dcen, int y, int x,
                                    int nyA, bool haveB,
                                    float& bestd, int& bestp) {
#pragma clang fp contract(off)
  int drA = nyA - y;
  par_pairs<DB, DE>(bufA, lane, fcx, fcy, fcz, dcen,
                    (float)(drA * drA), nyA * W + x, bestd, bestp);
  if (haveB) {
    int drB = nyA + 1 - y;
    par_pairs<DB, DE>(bufB, lane, fcx, fcy, fcz, dcen,
                      (float)(drB * drB), (nyA + 1) * W + x, bestd, bestp);
  }
}

__global__ __launch_bounds__(512, 4)
void k_par(const float4* __restrict__ pf, unsigned long long* __restrict__ pkeys) {
#pragma clang fp contract(off)
  __shared__ float4 aos[2][2][NSEG];       // [buf][row-of-pair][col]
  __shared__ unsigned long long m_k[8][64];
  int tid = threadIdx.x, lane = tid & 63, wave = tid >> 6;
  int b = blockIdx.x;                      // 1024 blocks, swizzled decode (R18)
  int y = ((b & 7) << 4) | ((b >> 3) & 15);
  int half = (b >> 7) & 1, tile = (b >> 8) & 1, img = (b >> 9) & 1;
  int x0 = tile * 64, x = x0 + lane;
  const float4* fimg = pf + img * PIMG;
  float4 fc = fimg[y * PSTR + x + KWIN];
  float dcen = fc.w;
  f32x2 fcx = { fc.x, fc.x }, fcy = { fc.y, fc.y }, fcz = { fc.z, fc.z };
  int ny0 = y - PR; if (ny0 < 0) ny0 = 0;
  int ny1 = y + PR; if (ny1 > H - 1) ny1 = H - 1;
  int nr = ny1 - ny0 + 1;                  // 21..41
  int h0 = nr >> 1;                        // rows in half 0
  int hb = half ? (ny0 + h0) : ny0;
  int he = half ? (ny1 + 1) : (ny0 + h0);
  int cnt = he - hb;                       // >= 10
  // pair staging: 2 rows x NSEG float4 = 2*208 float2; threads 0..207 stage
  // row A (float2 index sidx), threads 256..463 stage row B.
  int rsel = tid >> 8;                     // 0..1
  int sidx = tid & 255;                    // float2 index within row
  const int segoff = x0 + (KWIN - PR);     // staged cols = x0-PR .. x0+63+PR
  {
    int rA = hb;
    int rB = (hb + 1 < he) ? hb + 1 : hb;  // clamp (unused if no row B)
    int rr = rsel ? rB : rA;
    if (sidx < NSEG * 2) {
      float2 v = *(const float2*)(((const float*)(fimg + rr * PSTR + segoff)) + sidx * 2);
      *(float2*)(((float*)&aos[0][rsel][0]) + sidx * 2) = v;
    }
  }
  __syncthreads();
  float bestd = __builtin_inff();
  int bestp = y * W + x;
  int npairs = (cnt + 1) >> 1;
  for (int p = 0; p < npairs; ++p) {
    int kb = p & 1;
    float2 pv;
    bool pre = (p + 1 < npairs);
    if (pre) {                             // issue next-pair global loads early
      int nA = hb + 2 * (p + 1);
      int nB = (nA + 1 < he) ? nA + 1 : nA;
      int pr_row = rsel ? nB : nA;
      if (sidx < NSEG * 2)
        pv = *(const float2*)(((const float*)(fimg + pr_row * PSTR + segoff)) + sidx * 2);
    }
    int nyA = hb + 2 * p;
    bool haveB = (nyA + 1 < he);           // wave-uniform
    const float4* bufA = &aos[kb][0][0];
    const float4* bufB = &aos[kb][1][0];
    if      (wave == 0) par_two_rows< 0,  6>(bufA, bufB, lane, fcx, fcy, fcz, dcen, y, x, nyA, haveB, bestd, bestp);
    else if (wave == 1) par_two_rows< 6, 11>(bufA, bufB, lane, fcx, fcy, fcz, dcen, y, x, nyA, haveB, bestd, bestp);
    else if (wave == 2) par_two_rows<11, 16>(bufA, bufB, lane, fcx, fcy, fcz, dcen, y, x, nyA, haveB, bestd, bestp);
    else if (wave == 3) par_two_rows<16, 21>(bufA, bufB, lane, fcx, fcy, fcz, dcen, y, x, nyA, haveB, bestd, bestp);
    else if (wave == 4) par_two_rows<21, 26>(bufA, bufB, lane, fcx, fcy, fcz, dcen, y, x, nyA, haveB, bestd, bestp);
    else if (wave == 5) par_two_rows<26, 31>(bufA, bufB, lane, fcx, fcy, fcz, dcen, y, x, nyA, haveB, bestd, bestp);
    else if (wave == 6) par_two_rows<31, 36>(bufA, bufB, lane, fcx, fcy, fcz, dcen, y, x, nyA, haveB, bestd, bestp);
    else                par_two_rows<36, 41>(bufA, bufB, lane, fcx, fcy, fcz, dcen, y, x, nyA, haveB, bestd, bestp);
    if (pre && sidx < NSEG * 2)            // write other buffer: no race now
      *(float2*)(((float*)&aos[kb ^ 1][rsel][0]) + sidx * 2) = pv;
    __syncthreads();                       // publish next pair
  }
  // pack (d, q): inf (no candidate) sorts above all finite d
  m_k[wave][lane] =
      ((unsigned long long)__float_as_uint(bestd) << 32) | (unsigned)bestp;
  __syncthreads();
  if (wave == 0) {
    unsigned long long k = m_k[0][lane];
#pragma unroll
    for (int w = 1; w < 8; ++w) {
      unsigned long long kw = m_k[w][lane];
      k = (kw < k) ? kw : k;
    }
    pkeys[half * (IMGS * NP) + img * NP + y * W + x] = k;
  }
}

// ---------------- merge halves -> parent ---------------------------------------
__global__ void k_merge(const unsigned long long* __restrict__ pkeys,
                        int* __restrict__ parent) {
  int i = blockIdx.x * blockDim.x + threadIdx.x;
  if (i >= IMGS * NP) return;
  unsigned long long k0 = pkeys[i], k1 = pkeys[IMGS * NP + i];
  unsigned long long k = (k0 < k1) ? k0 : k1;
  float bd = __uint_as_float((unsigned)(k >> 32));
  int p = i % NP;
  parent[i] = (bd > 400.0f) ? p : (int)(k & 0xffffffffu);  // sqrt(d) > max_dist
}

// ---------------- root find via path-halving union-find (R31, validated) -------
// Races are BENIGN: every write replaces a parent with a strict ancestor
// (forest acyclic: density strictly increases along chains), so concurrent
// threads cooperatively compress shared paths — ~O(log) steps each. root[] is
// the chain's unique fixed point => bit-identical to a serial chase. Root
// flags (parent[i]==i) preserved: roots never rewritten; a non-root's new
// parent is an ancestor != itself.
__global__ void k_root(int* __restrict__ parent, int* __restrict__ root) {
  int i = blockIdx.x * blockDim.x + threadIdx.x;
  if (i >= IMGS * NP) return;
  int img = i / NP, p = i % NP;
  int* par = parent + img * NP;
  int v = p;
  int pr = par[v];
  int gp = par[pr];
  while (pr != gp) {
    par[v] = gp;                           // halve (benign race: gp = ancestor)
    v = gp;
    pr = par[v];
    gp = par[pr];
  }
  root[i] = pr;
}

// ---------------- scan of root flags + final labels (fused, coalesced) ---------
__global__ __launch_bounds__(1024)
void k_scanlabel(const int* __restrict__ parent, const int* __restrict__ root,
                 int* __restrict__ cums, int* __restrict__ out) {
  __shared__ int part[1024];
  int img = blockIdx.x;
  int t = threadIdx.x;                     // 1024 threads x 16 elements
  const int* par = parent + img * NP;
  int base = t * 16;
  int f[16];
  const int4* p4 = (const int4*)(par + base);
#pragma unroll
  for (int j = 0; j < 4; ++j) {
    int4 v = p4[j];
    f[4 * j + 0] = (v.x == base + 4 * j + 0);
    f[4 * j + 1] = (v.y == base + 4 * j + 1);
    f[4 * j + 2] = (v.z == base + 4 * j + 2);
    f[4 * j + 3] = (v.w == base + 4 * j + 3);
  }
  int s = 0;
#pragma unroll
  for (int j = 0; j < 16; ++j) s += f[j];
  part[t] = s;
  __syncthreads();
  for (int off = 1; off < 1024; off <<= 1) {
    int add = (t >= off) ? part[t - off] : 0;
    __syncthreads();
    part[t] += add;
    __syncthreads();
  }
  int run = part[t] - s;                   // exclusive prefix of this chunk
  int* c = cums + img * NP;
#pragma unroll
  for (int j = 0; j < 16; ++j) { run += f[j]; c[base + j] = run; }
  __threadfence_block();
  __syncthreads();                         // block-visible global writes
  const int* rimg = root + img * NP;
  int* oimg = out + img * NP;
  for (int j = t; j < NP; j += 1024) {
    int lab = c[rimg[j]] - 1;
    oimg[j] = (lab < MAXSEG - 1) ? lab : (MAXSEG - 1);
  }
}

extern "C" void kernel_launch(void* const* d_in, const int* in_sizes, int n_in,
                              void* d_out, int out_size, void* d_ws, size_t ws_size,
                              hipStream_t stream) {
  const float* x = (const float*)d_in[0];
  int* out = (int*)d_out;
  char* ws = (char*)d_ws;

  // workspace layout (~1.70 MB).
  // part (4 x IMGS*NP floats = 524288 B) aliases bufL — bufL dead after k_blur.
  // pkeys (2 x IMGS*NP u64 = 524288 B) aliases the same region — part dead
  // after k_densmerge; k_par writes pkeys after that (in-stream order).
  float4* pf   = (float4*)(ws);                         // 2*24576*16 = 786432
  float4* bufL = (float4*)(ws + 786432);                // 524288 (lab output)
  float* part  = (float*)(ws + 786432);                 // alias bufL, 524288
  unsigned long long* pkeys = (unsigned long long*)(ws + 786432);  // alias, 524288
  int* parent  = (int*)(ws + 1310720);                  // 131072
  int* root    = (int*)(ws + 1441792);                  // 131072
  int* cums    = (int*)(ws + 1572864);                  // 131072

  const int total = IMGS * NP;                          // 32768
  const int ptotal = IMGS * PIMG;                       // 49152

  k_prep<<<(ptotal + 255) / 256, 256, 0, stream>>>(x, pf, bufL);
  k_blur<<<IMGS * H, 384, 0, stream>>>(bufL, pf);
  k_dens<<<1024, 512, 0, stream>>>(pf, part);
  k_densmerge<<<total / 256, 256, 0, stream>>>(part, pf);
  k_par<<<1024, 512, 0, stream>>>(pf, pkeys);
  k_merge<<<total / 256, 256, 0, stream>>>(pkeys, parent);
  k_root<<<total / 256, 256, 0, stream>>>(parent, root);
  k_scanlabel<<<IMGS, 1024, 0, stream>>>(parent, root, cums, out);
}